// Round 15
// baseline (30521.716 us; speedup 1.0000x reference)
//
#include <hip/hip_runtime.h>

// ---------------- problem constants ----------------
#define TDEC 200
#define NB   16
#define PRE  256
#define RNN  1024

// ---------------- ws layout (float offsets) ----------------
#define PM_OFF   0u          // pm[16][512][128]  (transposed)
#define INP_OFF  1048576u    // inp[200][16][256]
#define HA_OFF   1867776u    // h_a[2][16][1024]
#define HD_OFF   1900544u    // h_d[2][16][1024]
#define CTX_OFF  1933312u    // ctx[2][16][512]
#define WB_OFF   1949696u    // w[16][512]
#define WC_OFF   1957888u    // wcum[16][512]
#define BAR_OFF  1966080u    // barrier (576 u32 + pad to 1024)
#define PE_OFF   1967104u    // pe[16][512][32]
#define W16_OFF  2229248u    // bf16 weights (u16): aih|ahh|dih|dhh
#define ZLEN_F   99328u      // zero HA..PE start

// u16 offsets within bf16 region
#define U16_AIH  0u
#define U16_AHH  3145728u    // 4096*768
#define U16_DIH  7340032u    // + 4096*1024
#define U16_DHH  13631488u   // + 4096*1536
#define U16_TOT  17825792u   // + 4096*1024

// LDS: acts [16][520] = 8320 | gate scratch [4][8][16] at 8320
#define ASTR 520
#define SCR  8320

typedef unsigned long long u64;
typedef float f32x4 __attribute__((ext_vector_type(4)));
typedef unsigned short u16;
union F2u { u64 u; float f[2]; };
union F4u { f32x4 v; float f[4]; };

__device__ __forceinline__ float sigm(float x)   { return 1.0f / (1.0f + __expf(-x)); }
__device__ __forceinline__ float tanh_f(float x) { return 1.0f - 2.0f / (__expf(2.0f * x) + 1.0f); }

__device__ __forceinline__ float dot4(float4 u, float4 v) {
    return u.x * v.x + u.y * v.y + u.z * v.z + u.w * v.w;
}
__device__ __forceinline__ void bf8(uint4 wv, float f[8]) {
    f[0] = __uint_as_float(wv.x << 16); f[1] = __uint_as_float(wv.x & 0xffff0000u);
    f[2] = __uint_as_float(wv.y << 16); f[3] = __uint_as_float(wv.y & 0xffff0000u);
    f[4] = __uint_as_float(wv.z << 16); f[5] = __uint_as_float(wv.z & 0xffff0000u);
    f[6] = __uint_as_float(wv.w << 16); f[7] = __uint_as_float(wv.w & 0xffff0000u);
}

__device__ __forceinline__ float ldc4(const float* p) {
    return __hip_atomic_load((float*)p, __ATOMIC_RELAXED, __HIP_MEMORY_SCOPE_AGENT);
}
__device__ __forceinline__ u64 ldc8u(const u64* p) {
    return __hip_atomic_load((u64*)p, __ATOMIC_RELAXED, __HIP_MEMORY_SCOPE_AGENT);
}
__device__ __forceinline__ void stc4(float* p, float v) {
    __hip_atomic_store(p, v, __ATOMIC_RELAXED, __HIP_MEMORY_SCOPE_AGENT);
}

#define LOAD1P_WAIT0(d0,p0) \
  asm volatile("global_load_dwordx4 %0, %1, off sc0 sc1\n\t" \
               "s_waitcnt vmcnt(0)" : "=&v"(d0) : "v"(p0) : "memory")

#define LOAD2P_WAIT0(d0,d1,p0,p1) \
  asm volatile("global_load_dwordx4 %0, %2, off sc0 sc1\n\t" \
               "global_load_dwordx4 %1, %3, off sc0 sc1\n\t" \
               "s_waitcnt vmcnt(0)" \
    : "=&v"(d0),"=&v"(d1) : "v"(p0),"v"(p1) : "memory")

#define LOADW4_WAIT0(d0,d1,d2,d3,p0,p1,p2,p3) \
  asm volatile("global_load_dwordx4 %0, %4, off\n\t" \
               "global_load_dwordx4 %1, %5, off\n\t" \
               "global_load_dwordx4 %2, %6, off\n\t" \
               "global_load_dwordx4 %3, %7, off\n\t" \
               "s_waitcnt vmcnt(0)" \
    : "=&v"(d0),"=&v"(d1),"=&v"(d2),"=&v"(d3) \
    : "v"(p0),"v"(p1),"v"(p2),"v"(p3) : "memory")

#define LOADW2_WAIT0(d0,d1,p0,p1) \
  asm volatile("global_load_dwordx4 %0, %2, off\n\t" \
               "global_load_dwordx4 %1, %3, off\n\t" \
               "s_waitcnt vmcnt(0)" \
    : "=&v"(d0),"=&v"(d1) : "v"(p0),"v"(p1) : "memory")

#define LOAD8P_WAIT0(d0,d1,d2,d3,d4,d5,d6,d7,p0,p1,p2,p3,p4,p5,p6,p7) \
  asm volatile("global_load_dwordx4 %0, %8, off sc0 sc1\n\t" \
               "global_load_dwordx4 %1, %9, off sc0 sc1\n\t" \
               "global_load_dwordx4 %2, %10, off sc0 sc1\n\t" \
               "global_load_dwordx4 %3, %11, off sc0 sc1\n\t" \
               "global_load_dwordx4 %4, %12, off sc0 sc1\n\t" \
               "global_load_dwordx4 %5, %13, off sc0 sc1\n\t" \
               "global_load_dwordx4 %6, %14, off sc0 sc1\n\t" \
               "global_load_dwordx4 %7, %15, off sc0 sc1\n\t" \
               "s_waitcnt vmcnt(0)" \
    : "=&v"(d0),"=&v"(d1),"=&v"(d2),"=&v"(d3),"=&v"(d4),"=&v"(d5),"=&v"(d6),"=&v"(d7) \
    : "v"(p0),"v"(p1),"v"(p2),"v"(p3),"v"(p4),"v"(p5),"v"(p6),"v"(p7) : "memory")

#define LOAD8X16_WAIT0(d0,d1,d2,d3,d4,d5,d6,d7,p) \
  asm volatile("global_load_dwordx4 %0, %8, off sc0 sc1\n\t" \
               "global_load_dwordx4 %1, %8, off offset:16 sc0 sc1\n\t" \
               "global_load_dwordx4 %2, %8, off offset:32 sc0 sc1\n\t" \
               "global_load_dwordx4 %3, %8, off offset:48 sc0 sc1\n\t" \
               "global_load_dwordx4 %4, %8, off offset:64 sc0 sc1\n\t" \
               "global_load_dwordx4 %5, %8, off offset:80 sc0 sc1\n\t" \
               "global_load_dwordx4 %6, %8, off offset:96 sc0 sc1\n\t" \
               "global_load_dwordx4 %7, %8, off offset:112 sc0 sc1\n\t" \
               "s_waitcnt vmcnt(0)" \
    : "=&v"(d0),"=&v"(d1),"=&v"(d2),"=&v"(d3),"=&v"(d4),"=&v"(d5),"=&v"(d6),"=&v"(d7) \
    : "v"(p) : "memory")

// ---- relaxed monotonic 2-level grid barrier (256 blocks) ----
__device__ __forceinline__ void grid_barrier(unsigned* bar, unsigned g)
{
    asm volatile("s_waitcnt vmcnt(0)" ::: "memory");
    __syncthreads();
    if (threadIdx.x == 0) {
        const int leaf = (blockIdx.x & 15) * 32;
        const unsigned tgt = g * 16u + 15u;
        if (__hip_atomic_fetch_add(&bar[leaf], 1u, __ATOMIC_RELAXED, __HIP_MEMORY_SCOPE_AGENT) == tgt) {
            if (__hip_atomic_fetch_add(&bar[512], 1u, __ATOMIC_RELAXED, __HIP_MEMORY_SCOPE_AGENT) == tgt) {
                __hip_atomic_store(&bar[544], g + 1u, __ATOMIC_RELAXED, __HIP_MEMORY_SCOPE_AGENT);
            } else {
                while (__hip_atomic_load(&bar[544], __ATOMIC_RELAXED, __HIP_MEMORY_SCOPE_AGENT) != g + 1u)
                    __builtin_amdgcn_s_sleep(4);
            }
        } else {
            while (__hip_atomic_load(&bar[544], __ATOMIC_RELAXED, __HIP_MEMORY_SCOPE_AGENT) != g + 1u)
                __builtin_amdgcn_s_sleep(4);
        }
    }
    __syncthreads();
}

__device__ __forceinline__ const float* act_src(bool isAtt, int c, int b,
    const float* inpT, const float* ctxP, const float* haP, const float* hdP2)
{
    if (isAtt) {
        if (c < 256)  return inpT + b * 256 + c;
        if (c < 768)  return ctxP + b * 512 + (c - 256);
        return haP + b * 1024 + (c - 768);
    } else {
        if (c < 1024) return haP + b * 1024 + c;
        if (c < 1536) return ctxP + b * 512 + (c - 1024);
        return hdP2 + b * 1024 + (c - 1536);
    }
}

// ---------------- fp32 -> bf16 (RNE) converter ----------------
__global__ __launch_bounds__(256) void k_cvt(const float* __restrict__ src,
                                             u16* __restrict__ dst, int n)
{
    const int stride = gridDim.x * 256;
    for (int i = blockIdx.x * 256 + threadIdx.x; i < n; i += stride) {
        const unsigned x = __float_as_uint(src[i]);
        const unsigned r = x + 0x7fffu + ((x >> 16) & 1u);
        dst[i] = (u16)(r >> 16);
    }
}

// ---------------- precompute: pm[b][tt][f] (transposed) ----------------
__global__ __launch_bounds__(256) void k_pm(const float* __restrict__ mem,
                                            const float* __restrict__ Wm,
                                            float* __restrict__ pm)
{
    const int bid = blockIdx.x;
    const int b = bid >> 5, ch = bid & 31;
    const int tid = threadIdx.x;
    const int tt0 = ch * 16;
    __shared__ float ml[16][512];
    for (int i = tid; i < 16 * 128; i += 256) {
        const int r = i >> 7, c4 = (i & 127) * 4;
        *(float4*)&ml[r][c4] = *(const float4*)(mem + (size_t)(b * 512 + tt0 + r) * 512 + c4);
    }
    __syncthreads();
    const int f = tid & 127, th = tid >> 7;
    float acc[8] = {0, 0, 0, 0, 0, 0, 0, 0};
    const float* wr = Wm + f * 512;
    for (int d = 0; d < 512; d += 4) {
        const float4 w4 = *(const float4*)(wr + d);
        #pragma unroll
        for (int i = 0; i < 8; ++i) {
            const float4 m4 = *(const float4*)&ml[th * 8 + i][d];
            acc[i] += dot4(w4, m4);
        }
    }
    #pragma unroll
    for (int i = 0; i < 8; ++i)
        pm[((size_t)(b * 512 + tt0 + th * 8 + i)) * 128 + f] = acc[i];
}

// ---------------- precompute: prenet ----------------
__global__ __launch_bounds__(256) void k_prenet(const float* __restrict__ di,
                                                const float* __restrict__ W1,
                                                const float* __restrict__ W2,
                                                float* __restrict__ inp)
{
    const int t = blockIdx.x;
    const int tid = threadIdx.x;
    float* inpT = inp + (size_t)t * (NB * PRE);
    if (t == 0) {
        for (int i = tid; i < NB * PRE; i += 256) inpT[i] = 0.0f;
        return;
    }
    const int s = t - 1;
    __shared__ float xs[16][240];
    __shared__ float h1[16][256];
    for (int i = tid; i < 16 * 240; i += 256) {
        const int b = i / 240, j2 = i % 240;
        xs[b][j2] = di[(size_t)b * 48000 + (j2 % 80) * 600 + s * 3 + j2 / 80];
    }
    __syncthreads();
    const int j = tid;
    {
        float acc[16];
        #pragma unroll
        for (int b = 0; b < 16; ++b) acc[b] = 0.0f;
        const float* wr = W1 + j * 240;
        for (int k = 0; k < 240; k += 4) {
            const float4 w4 = *(const float4*)(wr + k);
            #pragma unroll
            for (int b = 0; b < 16; ++b) {
                const float4 x4 = *(const float4*)&xs[b][k];
                acc[b] += dot4(w4, x4);
            }
        }
        #pragma unroll
        for (int b = 0; b < 16; ++b) h1[b][j] = fmaxf(acc[b], 0.0f);
    }
    __syncthreads();
    {
        float acc[16];
        #pragma unroll
        for (int b = 0; b < 16; ++b) acc[b] = 0.0f;
        const float* wr = W2 + j * 256;
        for (int k = 0; k < 256; k += 4) {
            const float4 w4 = *(const float4*)(wr + k);
            #pragma unroll
            for (int b = 0; b < 16; ++b) {
                const float4 x4 = *(const float4*)&h1[b][k];
                acc[b] += dot4(w4, x4);
            }
        }
        #pragma unroll
        for (int b = 0; b < 16; ++b) inpT[b * 256 + j] = fmaxf(acc[b], 0.0f);
    }
}

// ---------------- persistent decoder kernel: 256 blocks x 1024 threads ----------------
template<int BF16>
__global__ __launch_bounds__(1024) void k_main(
    const float* __restrict__ mem,  const int* __restrict__ mlen,
    const float* __restrict__ awih, const float* __restrict__ awhh,
    const float* __restrict__ abih, const float* __restrict__ abhh,
    const float* __restrict__ dwih, const float* __restrict__ dwhh,
    const float* __restrict__ dbih, const float* __restrict__ dbhh,
    const float* __restrict__ wq,   const float* __restrict__ vat,
    const float* __restrict__ cw,   const float* __restrict__ ldw,
    const float* __restrict__ pjw,  const float* __restrict__ pjb,
    float* __restrict__ ws, float* __restrict__ out)
{
    const int tid  = threadIdx.x;
    const int bid  = blockIdx.x;
    const int wid  = tid >> 6;
    const int lane = tid & 63;

    float* pmT  = ws + PM_OFF;
    float* inp  = ws + INP_OFF;
    float* haB  = ws + HA_OFF;
    float* hdB  = ws + HD_OFF;
    float* ctxB = ws + CTX_OFF;
    float* wBf  = ws + WB_OFF;
    float* wcB  = ws + WC_OFF;
    float* peB  = ws + PE_OFF;
    unsigned* bar = (unsigned*)(ws + BAR_OFF);
    const u16* w16 = (const u16*)(ws + W16_OFF);
    float* outMel = out;
    float* outAl  = out + 768000;

    __shared__ float smem[8832];    // acts [16][520] + gate scratch [4][8][16]
    unsigned gen = 0;
    float c_reg = 0.0f;             // persistent cell state, owned by tid<128

    const bool isAtt = (bid < 128);
    const int j0 = (isAtt ? bid : bid - 128) * 8;

    const float* wih = isAtt ? awih : dwih;
    const float* whh = isAtt ? awhh : dwhh;
    const u16* wih16 = w16 + (isAtt ? U16_AIH : U16_DIH);
    const u16* whh16 = w16 + (isAtt ? U16_AHH : U16_DHH);
    const int wihs = isAtt ? 768 : 1536;
    const int bnd  = wihs;
    const int K    = isAtt ? 1792 : 2560;
    const int nchk = (K + 511) >> 9;

    // wave task: gates {gA, gA+2} for row j0+jw
    const int gA = wid >> 3;
    const int jw = wid & 7;
    const int jj = j0 + jw;
    const size_t rAih = (size_t)(gA * 1024 + jj) * wihs;
    const size_t rBih = (size_t)((gA + 2) * 1024 + jj) * wihs;
    const size_t rAhh = (size_t)(gA * 1024 + jj) * 1024;
    const size_t rBhh = (size_t)((gA + 2) * 1024 + jj) * 1024;

    for (int t = 0; t <= TDEC; ++t) {
        const float* haP  = haB + ((t + 1) & 1) * (NB * RNN);
        float*       haC  = haB + (t & 1) * (NB * RNN);
        const float* hdP2 = hdB + (t & 1) * (NB * RNN);
        float*       hdW  = hdB + ((t + 1) & 1) * (NB * RNN);
        const float* ctxP = ctxB + ((t + 1) & 1) * (NB * 512);
        float*       ctxC = ctxB + (t & 1) * (NB * 512);
        const float* inpT = inp + (size_t)t * (NB * PRE);

        // ============ P1: gate GEMV — acts in LDS; weights fp32 or bf16 ============
        {
            const bool act = isAtt ? (t < TDEC) : (t >= 1);
            if (act) {
                float accA[16], accB[16];
                #pragma unroll
                for (int b = 0; b < 16; ++b) { accA[b] = 0.0f; accB[b] = 0.0f; }
                for (int chv = 0; chv < nchk; ++chv) {
                    const int c0 = chv << 9;
                    const int span = (K - c0 < 512) ? (K - c0) : 512;
                    // ---- stage acts -> LDS [b][ASTR] ----
                    if (span == 512) {
                        const int f0 = tid, f1 = tid + 1024;
                        const int b0 = f0 >> 7, c40 = f0 & 127;
                        const int b1 = f1 >> 7, c41 = f1 & 127;
                        const float* s0 = act_src(isAtt, c0 + c40 * 4, b0, inpT, ctxP, haP, hdP2);
                        const float* s1 = act_src(isAtt, c0 + c41 * 4, b1, inpT, ctxP, haP, hdP2);
                        float4 v0, v1;
                        LOAD2P_WAIT0(v0, v1, s0, s1);
                        *(float4*)&smem[b0 * ASTR + c40 * 4] = v0;
                        *(float4*)&smem[b1 * ASTR + c41 * 4] = v1;
                    } else {  // span 256
                        const int b0 = tid >> 6, c40 = tid & 63;
                        const float* s0 = act_src(isAtt, c0 + c40 * 4, b0, inpT, ctxP, haP, hdP2);
                        float4 v0;
                        LOAD1P_WAIT0(v0, s0);
                        *(float4*)&smem[b0 * ASTR + c40 * 4] = v0;
                    }
                    __syncthreads();
                    if constexpr (BF16) {
                        // lane covers 8 cols at c0+lane*8; one uint4 per gate-row
                        const int c = c0 + lane * 8;
                        if (c < K && (span == 512 || lane < 32)) {
                            const u16* pA = (c < bnd) ? (wih16 + rAih + c) : (whh16 + rAhh + (c - bnd));
                            const u16* pB = (c < bnd) ? (wih16 + rBih + c) : (whh16 + rBhh + (c - bnd));
                            const uint4 WA = *(const uint4*)pA;
                            const uint4 WB = *(const uint4*)pB;
                            float fa[8], fb[8];
                            bf8(WA, fa); bf8(WB, fb);
                            const int lc = lane * 8;
                            #pragma unroll
                            for (int b = 0; b < 16; ++b) {
                                const float4 a0 = *(const float4*)&smem[b * ASTR + lc];
                                const float4 a1 = *(const float4*)&smem[b * ASTR + lc + 4];
                                accA[b] += fa[0] * a0.x + fa[1] * a0.y + fa[2] * a0.z + fa[3] * a0.w
                                         + fa[4] * a1.x + fa[5] * a1.y + fa[6] * a1.z + fa[7] * a1.w;
                                accB[b] += fb[0] * a0.x + fb[1] * a0.y + fb[2] * a0.z + fb[3] * a0.w
                                         + fb[4] * a1.x + fb[5] * a1.y + fb[6] * a1.z + fb[7] * a1.w;
                            }
                        }
                    } else {
                        if (span == 512) {
                            const int cA = c0, cB = c0 + 256;
                            const float* pA0 = ((cA < bnd) ? (wih + rAih + cA) : (whh + rAhh + (cA - bnd))) + lane * 4;
                            const float* pA1 = ((cB < bnd) ? (wih + rAih + cB) : (whh + rAhh + (cB - bnd))) + lane * 4;
                            const float* pB0 = ((cA < bnd) ? (wih + rBih + cA) : (whh + rBhh + (cA - bnd))) + lane * 4;
                            const float* pB1 = ((cB < bnd) ? (wih + rBih + cB) : (whh + rBhh + (cB - bnd))) + lane * 4;
                            float4 wA0, wA1, wB0, wB1;
                            LOADW4_WAIT0(wA0, wA1, wB0, wB1, pA0, pA1, pB0, pB1);
                            #pragma unroll
                            for (int b = 0; b < 16; ++b) {
                                const float4 a0 = *(const float4*)&smem[b * ASTR + lane * 4];
                                const float4 a1 = *(const float4*)&smem[b * ASTR + 256 + lane * 4];
                                accA[b] += dot4(wA0, a0) + dot4(wA1, a1);
                                accB[b] += dot4(wB0, a0) + dot4(wB1, a1);
                            }
                        } else {
                            const int cA = c0;
                            const float* pA0 = ((cA < bnd) ? (wih + rAih + cA) : (whh + rAhh + (cA - bnd))) + lane * 4;
                            const float* pB0 = ((cA < bnd) ? (wih + rBih + cA) : (whh + rBhh + (cA - bnd))) + lane * 4;
                            float4 wA0, wB0;
                            LOADW2_WAIT0(wA0, wB0, pA0, pB0);
                            #pragma unroll
                            for (int b = 0; b < 16; ++b) {
                                const float4 a0 = *(const float4*)&smem[b * ASTR + lane * 4];
                                accA[b] += dot4(wA0, a0);
                                accB[b] += dot4(wB0, a0);
                            }
                        }
                    }
                    __syncthreads();
                }
                // ---- reduce across 64 lanes; predicated scratch write ----
                #pragma unroll
                for (int m = 1; m <= 32; m <<= 1) {
                    #pragma unroll
                    for (int b = 0; b < 16; ++b) {
                        accA[b] += __shfl_xor(accA[b], m, 64);
                        accB[b] += __shfl_xor(accB[b], m, 64);
                    }
                }
                #pragma unroll
                for (int b = 0; b < 16; ++b) {
                    if (lane == b) {
                        smem[SCR + gA * 128 + jw * 16 + b]       = accA[b];
                        smem[SCR + (gA + 2) * 128 + jw * 16 + b] = accB[b];
                    }
                }
                __syncthreads();
                if (tid < 128) {   // LSTM epilogue
                    const int b = tid >> 3, jb = tid & 7;
                    const int j = j0 + jb;
                    const float* bih = isAtt ? abih : dbih;
                    const float* bhh = isAtt ? abhh : dbhh;
                    float g4[4];
                    #pragma unroll
                    for (int g = 0; g < 4; ++g)
                        g4[g] = smem[SCR + g * 128 + jb * 16 + b]
                              + bih[g * 1024 + j] + bhh[g * 1024 + j];
                    const float ii = sigm(g4[0]), ff = sigm(g4[1]);
                    const float gg = tanh_f(g4[2]), oo = sigm(g4[3]);
                    c_reg = ff * c_reg + ii * gg;
                    float* hb = isAtt ? haC : hdW;
                    stc4(&hb[b * RNN + j], oo * tanh_f(c_reg));
                }
            }
        }
        grid_barrier(bar, gen); ++gen;

        // ================= P2: q-GEMV + conv + energies (32 tt per block) =================
        if (t < TDEC) {
            const int b2 = bid & 15, ts = bid >> 4;
            float* smemH  = smem;          // [1024]
            float* smemW  = smem + 1024;   // [62]
            float* smemWC = smem + 1104;   // [62]
            float* smemQ  = smem + 1184;   // [128]
            float* smemL  = smem + 1312;   // [32*33]
            if (tid < 512) {
                F2u v; v.u = ldc8u((const u64*)(haC + b2 * 1024) + tid);
                smemH[tid * 2] = v.f[0]; smemH[tid * 2 + 1] = v.f[1];
            } else if (tid < 574) {
                const int i = tid - 512;
                const int ix = ts * 32 - 15 + i;
                smemW[i] = (ix >= 0 && ix < 512) ? ldc4(wBf + b2 * 512 + ix) : 0.0f;
            } else if (tid < 636) {
                const int i = tid - 574;
                const int ix = ts * 32 - 15 + i;
                smemWC[i] = (ix >= 0 && ix < 512) ? ldc4(wcB + b2 * 512 + ix) : 0.0f;
            }
            __syncthreads();
            {
                const float4 h0 = *(const float4*)&smemH[lane * 4];
                const float4 h1 = *(const float4*)&smemH[lane * 4 + 256];
                const float4 h2 = *(const float4*)&smemH[lane * 4 + 512];
                const float4 h3 = *(const float4*)&smemH[lane * 4 + 768];
                #pragma unroll
                for (int fl = 0; fl < 8; ++fl) {
                    const int f = wid * 8 + fl;
                    const float* wqr = wq + (size_t)f * 1024 + lane * 4;
                    const float4 w0 = *(const float4*)(wqr);
                    const float4 w1 = *(const float4*)(wqr + 256);
                    const float4 w2 = *(const float4*)(wqr + 512);
                    const float4 w3 = *(const float4*)(wqr + 768);
                    float aq = dot4(w0, h0) + dot4(w1, h1) + dot4(w2, h2) + dot4(w3, h3);
                    #pragma unroll
                    for (int m = 1; m <= 32; m <<= 1) aq += __shfl_xor(aq, m, 64);
                    if (lane == 0) smemQ[f] = aq;
                }
            }
            __syncthreads();
            {
                const int ttl = tid >> 5, ch = tid & 31;
                const float* cwc = cw + ch * 62;
                float a = 0.0f;
                #pragma unroll
                for (int kk = 0; kk < 31; ++kk)
                    a += smemW[ttl + kk] * cwc[kk] + smemWC[ttl + kk] * cwc[31 + kk];
                smemL[ttl * 33 + ch] = a;
            }
            __syncthreads();
            {
                const int ttl = tid >> 5, fq = tid & 31;
                const int tt = ts * 32 + ttl;
                const float* lrow = smemL + ttl * 33;
                F4u pm4; pm4.v = __builtin_nontemporal_load(
                    (const f32x4*)(pmT + ((size_t)(b2 * 512 + tt)) * 128 + fq * 4));
                float pes = 0.0f;
                #pragma unroll
                for (int i = 0; i < 4; ++i) {
                    const int f = fq * 4 + i;
                    const float* lw = ldw + f * 32;
                    float pl = 0.0f;
                    #pragma unroll
                    for (int c2 = 0; c2 < 32; ++c2) pl += lrow[c2] * lw[c2];
                    const float x = smemQ[f] + pl + pm4.f[i];
                    pes += vat[f] * tanh_f(x);
                }
                stc4(peB + ((size_t)(b2 * 512 + tt)) * 32 + fq, pes);
            }
        }
        grid_barrier(bar, gen); ++gen;

        // ================= P3: softmax/ctx (blocks 0-63) + proj (64-93) =================
        if (bid < 64) {
            if (t < TDEC) {
                const int b3 = bid & 15, dq = bid >> 4;
                float* pl_ = smem;          // [512]
                float* red = smem + 512;    // [17]
                float* psm = smem + 544;    // [1024]
                if (tid < 512) {
                    const int tt = tid;
                    float4 l0, l1, l2, l3, l4, l5, l6, l7;
                    LOAD8X16_WAIT0(l0, l1, l2, l3, l4, l5, l6, l7,
                                   peB + ((size_t)(b3 * 512 + tt)) * 32);
                    float e = l0.x + l0.y + l0.z + l0.w + l1.x + l1.y + l1.z + l1.w
                            + l2.x + l2.y + l2.z + l2.w + l3.x + l3.y + l3.z + l3.w
                            + l4.x + l4.y + l4.z + l4.w + l5.x + l5.y + l5.z + l5.w
                            + l6.x + l6.y + l6.z + l6.w + l7.x + l7.y + l7.z + l7.w;
                    const float p = (tt < mlen[b3]) ? __expf(e) : 0.0f;
                    pl_[tt] = p;
                    float sred = p;
                    #pragma unroll
                    for (int m = 1; m <= 32; m <<= 1) sred += __shfl_xor(sred, m, 64);
                    if (lane == 0) red[wid] = sred;
                }
                __syncthreads();
                if (tid == 0) {
                    float d = 0.0f;
                    #pragma unroll
                    for (int w = 0; w < 8; ++w) d += red[w];
                    red[8] = 1.0f / d;
                }
                __syncthreads();
                const float rd = red[8];
                {
                    const int dl = tid & 127, part = tid >> 7;
                    const float* mr = mem + (size_t)b3 * (512 * 512) + dq * 128 + dl;
                    float a = 0.0f;
                    const int r0 = part * 64;
                    for (int r2_ = 0; r2_ < 64; ++r2_)
                        a += pl_[r0 + r2_] * __builtin_nontemporal_load(mr + (size_t)(r0 + r2_) * 512);
                    psm[dl * 8 + part] = a;
                }
                __syncthreads();
                if (tid < 128) {
                    float a = 0.0f;
                    #pragma unroll
                    for (int p2 = 0; p2 < 8; ++p2) a += psm[tid * 8 + p2];
                    stc4(&ctxC[b3 * 512 + dq * 128 + tid], a * rd);
                }
                if (dq == 0 && tid < 512) {
                    const float wn = pl_[tid] * rd;
                    stc4(&wBf[b3 * 512 + tid], wn);
                    stc4(&wcB[b3 * 512 + tid], ldc4(&wcB[b3 * 512 + tid]) + wn);
                    outAl[(size_t)b3 * (200 * 512) + (size_t)t * 512 + tid] = wn;
                }
            }
        } else if (bid < 94) {
            if (t >= 1) {
                const int jo = (bid - 64) * 8 + (wid >> 1);
                const int bh = wid & 1;
                const float* pwr = pjw + (size_t)jo * 1536 + lane * 4;
                float a[8] = {0, 0, 0, 0, 0, 0, 0, 0};
                #pragma unroll
                for (int pass = 0; pass < 6; ++pass) {
                    const int k = pass * 256 + lane * 4;
                    const float* qp[8];
                    #pragma unroll
                    for (int i = 0; i < 8; ++i) {
                        const int b = bh * 8 + i;
                        qp[i] = (pass < 4) ? (hdW + b * 1024 + k) : (ctxP + b * 512 + (k - 1024));
                    }
                    float4 c0, c1, c2, c3, c4, c5, c6, c7;
                    LOAD8P_WAIT0(c0, c1, c2, c3, c4, c5, c6, c7,
                                 qp[0], qp[1], qp[2], qp[3], qp[4], qp[5], qp[6], qp[7]);
                    const float4 w4 = *(const float4*)(pwr + pass * 256);
                    a[0] += dot4(w4, c0); a[1] += dot4(w4, c1);
                    a[2] += dot4(w4, c2); a[3] += dot4(w4, c3);
                    a[4] += dot4(w4, c4); a[5] += dot4(w4, c5);
                    a[6] += dot4(w4, c6); a[7] += dot4(w4, c7);
                }
                #pragma unroll
                for (int i = 0; i < 8; ++i)
                    #pragma unroll
                    for (int m = 1; m <= 32; m <<= 1) a[i] += __shfl_xor(a[i], m, 64);
                if (lane == 0) {
                    const int m_ = jo % 80;
                    const int u = (t - 1) * 3 + jo / 80;
                    const float bv = pjb[jo];
                    #pragma unroll
                    for (int i = 0; i < 8; ++i)
                        outMel[(size_t)(bh * 8 + i) * 48000 + m_ * 600 + u] = a[i] + bv;
                }
            }
        }
        grid_barrier(bar, gen); ++gen;
    }
}

extern "C" void kernel_launch(void* const* d_in, const int* in_sizes, int n_in,
                              void* d_out, int out_size, void* d_ws, size_t ws_size,
                              hipStream_t stream)
{
    (void)in_sizes; (void)n_in; (void)out_size;
    const float* mem  = (const float*)d_in[0];
    const float* di   = (const float*)d_in[1];
    const int*   mlen = (const int*)d_in[2];
    const float* pw1  = (const float*)d_in[3];
    const float* pw2  = (const float*)d_in[4];
    const float* awih = (const float*)d_in[5];
    const float* awhh = (const float*)d_in[6];
    const float* abih = (const float*)d_in[7];
    const float* abhh = (const float*)d_in[8];
    const float* dwih = (const float*)d_in[9];
    const float* dwhh = (const float*)d_in[10];
    const float* dbih = (const float*)d_in[11];
    const float* dbhh = (const float*)d_in[12];
    const float* wqp  = (const float*)d_in[13];
    const float* wmp  = (const float*)d_in[14];
    const float* vat  = (const float*)d_in[15];
    const float* cwp  = (const float*)d_in[16];
    const float* ldwp = (const float*)d_in[17];
    const float* pjw  = (const float*)d_in[18];
    const float* pjb  = (const float*)d_in[19];
    float* ws  = (float*)d_ws;
    float* out = (float*)d_out;

    const size_t needB = (size_t)W16_OFF * 4 + (size_t)U16_TOT * 2;
    const bool useBf16 = (ws_size >= needB);

    hipMemsetAsync(ws + HA_OFF, 0, ZLEN_F * sizeof(float), stream);
    hipLaunchKernelGGL(k_pm, dim3(512), dim3(256), 0, stream, mem, wmp, ws + PM_OFF);
    hipLaunchKernelGGL(k_prenet, dim3(200), dim3(256), 0, stream, di, pw1, pw2, ws + INP_OFF);
    if (useBf16) {
        u16* w16 = (u16*)(ws + W16_OFF);
        hipLaunchKernelGGL(k_cvt, dim3(512), dim3(256), 0, stream, awih, w16 + U16_AIH, 4096 * 768);
        hipLaunchKernelGGL(k_cvt, dim3(512), dim3(256), 0, stream, awhh, w16 + U16_AHH, 4096 * 1024);
        hipLaunchKernelGGL(k_cvt, dim3(512), dim3(256), 0, stream, dwih, w16 + U16_DIH, 4096 * 1536);
        hipLaunchKernelGGL(k_cvt, dim3(512), dim3(256), 0, stream, dwhh, w16 + U16_DHH, 4096 * 1024);
    }

    void* args[] = { (void*)&mem, (void*)&mlen, (void*)&awih, (void*)&awhh,
                     (void*)&abih, (void*)&abhh, (void*)&dwih, (void*)&dwhh,
                     (void*)&dbih, (void*)&dbhh, (void*)&wqp, (void*)&vat,
                     (void*)&cwp, (void*)&ldwp, (void*)&pjw, (void*)&pjb,
                     (void*)&ws, (void*)&out };
    if (useBf16)
        hipLaunchCooperativeKernel((const void*)k_main<1>, dim3(256), dim3(1024), args, 0, stream);
    else
        hipLaunchCooperativeKernel((const void*)k_main<0>, dim3(256), dim3(1024), args, 0, stream);
}

// Round 16
// 24560.118 us; speedup vs baseline: 1.2427x; 1.2427x over previous
//
#include <hip/hip_runtime.h>

// ---------------- problem constants ----------------
#define TDEC 200
#define NB   16
#define PRE  256
#define RNN  1024

// ---------------- ws layout (float offsets) ----------------
#define PM_OFF   0u          // pm[16][512][128]  (transposed)
#define INP_OFF  1048576u    // inp[200][16][256]
#define HA_OFF   1867776u    // h_a[2][16][1024]
#define HD_OFF   1900544u    // h_d[2][16][1024]
#define CTX_OFF  1933312u    // ctx[2][16][512]
#define WB_OFF   1949696u    // w[16][512]
#define WC_OFF   1957888u    // wcum[16][512]
#define BAR_OFF  1966080u    // barrier (576 u32 + pad to 1024)
#define PE_OFF   1967104u    // pe[16][512][32]
#define W16_OFF  2229248u    // bf16 weights (u16): aih|ahh|dih|dhh
#define ZLEN_F   99328u      // zero HA..PE start

// u16 offsets within bf16 region
#define U16_AIH  0u
#define U16_AHH  3145728u    // 4096*768
#define U16_DIH  7340032u    // + 4096*1024
#define U16_DHH  13631488u   // + 4096*1536
#define U16_TOT  17825792u   // + 4096*1024

// LDS: acts [16][520] = 8320 | gate scratch [4][8][16] at 8320
#define ASTR 520
#define SCR  8320

typedef unsigned long long u64;
typedef float f32x4 __attribute__((ext_vector_type(4)));
typedef unsigned short u16;
union F2u { u64 u; float f[2]; };
union F4u { f32x4 v; float f[4]; };

__device__ __forceinline__ float sigm(float x)   { return 1.0f / (1.0f + __expf(-x)); }
__device__ __forceinline__ float tanh_f(float x) { return 1.0f - 2.0f / (__expf(2.0f * x) + 1.0f); }

__device__ __forceinline__ float dot4(float4 u, float4 v) {
    return u.x * v.x + u.y * v.y + u.z * v.z + u.w * v.w;
}
// expand 4 bf16 (packed in u64) -> float4
__device__ __forceinline__ float4 bfx4(u64 v) {
    const unsigned lo = (unsigned)v, hi = (unsigned)(v >> 32);
    float4 r;
    r.x = __uint_as_float(lo << 16);
    r.y = __uint_as_float(lo & 0xffff0000u);
    r.z = __uint_as_float(hi << 16);
    r.w = __uint_as_float(hi & 0xffff0000u);
    return r;
}

__device__ __forceinline__ float ldc4(const float* p) {
    return __hip_atomic_load((float*)p, __ATOMIC_RELAXED, __HIP_MEMORY_SCOPE_AGENT);
}
__device__ __forceinline__ u64 ldc8u(const u64* p) {
    return __hip_atomic_load((u64*)p, __ATOMIC_RELAXED, __HIP_MEMORY_SCOPE_AGENT);
}
__device__ __forceinline__ void stc4(float* p, float v) {
    __hip_atomic_store(p, v, __ATOMIC_RELAXED, __HIP_MEMORY_SCOPE_AGENT);
}

#define LOAD1P_WAIT0(d0,p0) \
  asm volatile("global_load_dwordx4 %0, %1, off sc0 sc1\n\t" \
               "s_waitcnt vmcnt(0)" : "=&v"(d0) : "v"(p0) : "memory")

#define LOAD2P_WAIT0(d0,d1,p0,p1) \
  asm volatile("global_load_dwordx4 %0, %2, off sc0 sc1\n\t" \
               "global_load_dwordx4 %1, %3, off sc0 sc1\n\t" \
               "s_waitcnt vmcnt(0)" \
    : "=&v"(d0),"=&v"(d1) : "v"(p0),"v"(p1) : "memory")

// fp32 weights: 16B cached loads + drain
#define LOADW4_WAIT0(d0,d1,d2,d3,p0,p1,p2,p3) \
  asm volatile("global_load_dwordx4 %0, %4, off\n\t" \
               "global_load_dwordx4 %1, %5, off\n\t" \
               "global_load_dwordx4 %2, %6, off\n\t" \
               "global_load_dwordx4 %3, %7, off\n\t" \
               "s_waitcnt vmcnt(0)" \
    : "=&v"(d0),"=&v"(d1),"=&v"(d2),"=&v"(d3) \
    : "v"(p0),"v"(p1),"v"(p2),"v"(p3) : "memory")

#define LOADW2_WAIT0(d0,d1,p0,p1) \
  asm volatile("global_load_dwordx4 %0, %2, off\n\t" \
               "global_load_dwordx4 %1, %3, off\n\t" \
               "s_waitcnt vmcnt(0)" \
    : "=&v"(d0),"=&v"(d1) : "v"(p0),"v"(p1) : "memory")

// bf16 weights: 8B cached loads + drain
#define LOADB4_WAIT0(d0,d1,d2,d3,p0,p1,p2,p3) \
  asm volatile("global_load_dwordx2 %0, %4, off\n\t" \
               "global_load_dwordx2 %1, %5, off\n\t" \
               "global_load_dwordx2 %2, %6, off\n\t" \
               "global_load_dwordx2 %3, %7, off\n\t" \
               "s_waitcnt vmcnt(0)" \
    : "=&v"(d0),"=&v"(d1),"=&v"(d2),"=&v"(d3) \
    : "v"(p0),"v"(p1),"v"(p2),"v"(p3) : "memory")

#define LOADB2_WAIT0(d0,d1,p0,p1) \
  asm volatile("global_load_dwordx2 %0, %2, off\n\t" \
               "global_load_dwordx2 %1, %3, off\n\t" \
               "s_waitcnt vmcnt(0)" \
    : "=&v"(d0),"=&v"(d1) : "v"(p0),"v"(p1) : "memory")

#define LOAD8P_WAIT0(d0,d1,d2,d3,d4,d5,d6,d7,p0,p1,p2,p3,p4,p5,p6,p7) \
  asm volatile("global_load_dwordx4 %0, %8, off sc0 sc1\n\t" \
               "global_load_dwordx4 %1, %9, off sc0 sc1\n\t" \
               "global_load_dwordx4 %2, %10, off sc0 sc1\n\t" \
               "global_load_dwordx4 %3, %11, off sc0 sc1\n\t" \
               "global_load_dwordx4 %4, %12, off sc0 sc1\n\t" \
               "global_load_dwordx4 %5, %13, off sc0 sc1\n\t" \
               "global_load_dwordx4 %6, %14, off sc0 sc1\n\t" \
               "global_load_dwordx4 %7, %15, off sc0 sc1\n\t" \
               "s_waitcnt vmcnt(0)" \
    : "=&v"(d0),"=&v"(d1),"=&v"(d2),"=&v"(d3),"=&v"(d4),"=&v"(d5),"=&v"(d6),"=&v"(d7) \
    : "v"(p0),"v"(p1),"v"(p2),"v"(p3),"v"(p4),"v"(p5),"v"(p6),"v"(p7) : "memory")

#define LOAD8X16_WAIT0(d0,d1,d2,d3,d4,d5,d6,d7,p) \
  asm volatile("global_load_dwordx4 %0, %8, off sc0 sc1\n\t" \
               "global_load_dwordx4 %1, %8, off offset:16 sc0 sc1\n\t" \
               "global_load_dwordx4 %2, %8, off offset:32 sc0 sc1\n\t" \
               "global_load_dwordx4 %3, %8, off offset:48 sc0 sc1\n\t" \
               "global_load_dwordx4 %4, %8, off offset:64 sc0 sc1\n\t" \
               "global_load_dwordx4 %5, %8, off offset:80 sc0 sc1\n\t" \
               "global_load_dwordx4 %6, %8, off offset:96 sc0 sc1\n\t" \
               "global_load_dwordx4 %7, %8, off offset:112 sc0 sc1\n\t" \
               "s_waitcnt vmcnt(0)" \
    : "=&v"(d0),"=&v"(d1),"=&v"(d2),"=&v"(d3),"=&v"(d4),"=&v"(d5),"=&v"(d6),"=&v"(d7) \
    : "v"(p) : "memory")

// ---- relaxed monotonic 2-level grid barrier (256 blocks) ----
__device__ __forceinline__ void grid_barrier(unsigned* bar, unsigned g)
{
    asm volatile("s_waitcnt vmcnt(0)" ::: "memory");
    __syncthreads();
    if (threadIdx.x == 0) {
        const int leaf = (blockIdx.x & 15) * 32;
        const unsigned tgt = g * 16u + 15u;
        if (__hip_atomic_fetch_add(&bar[leaf], 1u, __ATOMIC_RELAXED, __HIP_MEMORY_SCOPE_AGENT) == tgt) {
            if (__hip_atomic_fetch_add(&bar[512], 1u, __ATOMIC_RELAXED, __HIP_MEMORY_SCOPE_AGENT) == tgt) {
                __hip_atomic_store(&bar[544], g + 1u, __ATOMIC_RELAXED, __HIP_MEMORY_SCOPE_AGENT);
            } else {
                while (__hip_atomic_load(&bar[544], __ATOMIC_RELAXED, __HIP_MEMORY_SCOPE_AGENT) != g + 1u)
                    __builtin_amdgcn_s_sleep(4);
            }
        } else {
            while (__hip_atomic_load(&bar[544], __ATOMIC_RELAXED, __HIP_MEMORY_SCOPE_AGENT) != g + 1u)
                __builtin_amdgcn_s_sleep(4);
        }
    }
    __syncthreads();
}

__device__ __forceinline__ const float* act_src(bool isAtt, int c, int b,
    const float* inpT, const float* ctxP, const float* haP, const float* hdP2)
{
    if (isAtt) {
        if (c < 256)  return inpT + b * 256 + c;
        if (c < 768)  return ctxP + b * 512 + (c - 256);
        return haP + b * 1024 + (c - 768);
    } else {
        if (c < 1024) return haP + b * 1024 + c;
        if (c < 1536) return ctxP + b * 512 + (c - 1024);
        return hdP2 + b * 1024 + (c - 1536);
    }
}

// ---------------- fp32 -> bf16 (RNE) converter ----------------
__global__ __launch_bounds__(256) void k_cvt(const float* __restrict__ src,
                                             u16* __restrict__ dst, int n)
{
    const int stride = gridDim.x * 256;
    for (int i = blockIdx.x * 256 + threadIdx.x; i < n; i += stride) {
        const unsigned x = __float_as_uint(src[i]);
        const unsigned r = x + 0x7fffu + ((x >> 16) & 1u);
        dst[i] = (u16)(r >> 16);
    }
}

// ---------------- precompute: pm[b][tt][f] (transposed) ----------------
__global__ __launch_bounds__(256) void k_pm(const float* __restrict__ mem,
                                            const float* __restrict__ Wm,
                                            float* __restrict__ pm)
{
    const int bid = blockIdx.x;
    const int b = bid >> 5, ch = bid & 31;
    const int tid = threadIdx.x;
    const int tt0 = ch * 16;
    __shared__ float ml[16][512];
    for (int i = tid; i < 16 * 128; i += 256) {
        const int r = i >> 7, c4 = (i & 127) * 4;
        *(float4*)&ml[r][c4] = *(const float4*)(mem + (size_t)(b * 512 + tt0 + r) * 512 + c4);
    }
    __syncthreads();
    const int f = tid & 127, th = tid >> 7;
    float acc[8] = {0, 0, 0, 0, 0, 0, 0, 0};
    const float* wr = Wm + f * 512;
    for (int d = 0; d < 512; d += 4) {
        const float4 w4 = *(const float4*)(wr + d);
        #pragma unroll
        for (int i = 0; i < 8; ++i) {
            const float4 m4 = *(const float4*)&ml[th * 8 + i][d];
            acc[i] += dot4(w4, m4);
        }
    }
    #pragma unroll
    for (int i = 0; i < 8; ++i)
        pm[((size_t)(b * 512 + tt0 + th * 8 + i)) * 128 + f] = acc[i];
}

// ---------------- precompute: prenet ----------------
__global__ __launch_bounds__(256) void k_prenet(const float* __restrict__ di,
                                                const float* __restrict__ W1,
                                                const float* __restrict__ W2,
                                                float* __restrict__ inp)
{
    const int t = blockIdx.x;
    const int tid = threadIdx.x;
    float* inpT = inp + (size_t)t * (NB * PRE);
    if (t == 0) {
        for (int i = tid; i < NB * PRE; i += 256) inpT[i] = 0.0f;
        return;
    }
    const int s = t - 1;
    __shared__ float xs[16][240];
    __shared__ float h1[16][256];
    for (int i = tid; i < 16 * 240; i += 256) {
        const int b = i / 240, j2 = i % 240;
        xs[b][j2] = di[(size_t)b * 48000 + (j2 % 80) * 600 + s * 3 + j2 / 80];
    }
    __syncthreads();
    const int j = tid;
    {
        float acc[16];
        #pragma unroll
        for (int b = 0; b < 16; ++b) acc[b] = 0.0f;
        const float* wr = W1 + j * 240;
        for (int k = 0; k < 240; k += 4) {
            const float4 w4 = *(const float4*)(wr + k);
            #pragma unroll
            for (int b = 0; b < 16; ++b) {
                const float4 x4 = *(const float4*)&xs[b][k];
                acc[b] += dot4(w4, x4);
            }
        }
        #pragma unroll
        for (int b = 0; b < 16; ++b) h1[b][j] = fmaxf(acc[b], 0.0f);
    }
    __syncthreads();
    {
        float acc[16];
        #pragma unroll
        for (int b = 0; b < 16; ++b) acc[b] = 0.0f;
        const float* wr = W2 + j * 256;
        for (int k = 0; k < 256; k += 4) {
            const float4 w4 = *(const float4*)(wr + k);
            #pragma unroll
            for (int b = 0; b < 16; ++b) {
                const float4 x4 = *(const float4*)&h1[b][k];
                acc[b] += dot4(w4, x4);
            }
        }
        #pragma unroll
        for (int b = 0; b < 16; ++b) inpT[b * 256 + j] = fmaxf(acc[b], 0.0f);
    }
}

// ---------------- persistent decoder kernel: 256 blocks x 1024 threads ----------------
template<int BF16>
__global__ __launch_bounds__(1024) void k_main(
    const float* __restrict__ mem,  const int* __restrict__ mlen,
    const float* __restrict__ awih, const float* __restrict__ awhh,
    const float* __restrict__ abih, const float* __restrict__ abhh,
    const float* __restrict__ dwih, const float* __restrict__ dwhh,
    const float* __restrict__ dbih, const float* __restrict__ dbhh,
    const float* __restrict__ wq,   const float* __restrict__ vat,
    const float* __restrict__ cw,   const float* __restrict__ ldw,
    const float* __restrict__ pjw,  const float* __restrict__ pjb,
    float* __restrict__ ws, float* __restrict__ out)
{
    const int tid  = threadIdx.x;
    const int bid  = blockIdx.x;
    const int wid  = tid >> 6;
    const int lane = tid & 63;

    float* pmT  = ws + PM_OFF;
    float* inp  = ws + INP_OFF;
    float* haB  = ws + HA_OFF;
    float* hdB  = ws + HD_OFF;
    float* ctxB = ws + CTX_OFF;
    float* wBf  = ws + WB_OFF;
    float* wcB  = ws + WC_OFF;
    float* peB  = ws + PE_OFF;
    unsigned* bar = (unsigned*)(ws + BAR_OFF);
    const u16* w16 = (const u16*)(ws + W16_OFF);
    float* outMel = out;
    float* outAl  = out + 768000;

    __shared__ float smem[8832];    // acts [16][520] + gate scratch [4][8][16]
    unsigned gen = 0;
    float c_reg = 0.0f;             // persistent cell state, owned by tid<128

    const bool isAtt = (bid < 128);
    const int j0 = (isAtt ? bid : bid - 128) * 8;

    const float* wih = isAtt ? awih : dwih;
    const float* whh = isAtt ? awhh : dwhh;
    const u16* wih16 = w16 + (isAtt ? U16_AIH : U16_DIH);
    const u16* whh16 = w16 + (isAtt ? U16_AHH : U16_DHH);
    const int wihs = isAtt ? 768 : 1536;
    const int bnd  = wihs;
    const int K    = isAtt ? 1792 : 2560;
    const int nchk = (K + 511) >> 9;

    // wave task: gates {gA, gA+2} for row j0+jw
    const int gA = wid >> 3;
    const int jw = wid & 7;
    const int jj = j0 + jw;
    const size_t rAih = (size_t)(gA * 1024 + jj) * wihs;
    const size_t rBih = (size_t)((gA + 2) * 1024 + jj) * wihs;
    const size_t rAhh = (size_t)(gA * 1024 + jj) * 1024;
    const size_t rBhh = (size_t)((gA + 2) * 1024 + jj) * 1024;

    for (int t = 0; t <= TDEC; ++t) {
        const float* haP  = haB + ((t + 1) & 1) * (NB * RNN);
        float*       haC  = haB + (t & 1) * (NB * RNN);
        const float* hdP2 = hdB + (t & 1) * (NB * RNN);
        float*       hdW  = hdB + ((t + 1) & 1) * (NB * RNN);
        const float* ctxP = ctxB + ((t + 1) & 1) * (NB * 512);
        float*       ctxC = ctxB + (t & 1) * (NB * 512);
        const float* inpT = inp + (size_t)t * (NB * PRE);

        // ============ P1: gate GEMV — acts in LDS; weights fp32 or bf16 ============
        {
            const bool act = isAtt ? (t < TDEC) : (t >= 1);
            if (act) {
                float accA[16], accB[16];
                #pragma unroll
                for (int b = 0; b < 16; ++b) { accA[b] = 0.0f; accB[b] = 0.0f; }
                for (int chv = 0; chv < nchk; ++chv) {
                    const int c0 = chv << 9;
                    const int span = (K - c0 < 512) ? (K - c0) : 512;
                    // ---- stage acts -> LDS [b][ASTR] ----
                    if (span == 512) {
                        const int f0 = tid, f1 = tid + 1024;
                        const int b0 = f0 >> 7, c40 = f0 & 127;
                        const int b1 = f1 >> 7, c41 = f1 & 127;
                        const float* s0 = act_src(isAtt, c0 + c40 * 4, b0, inpT, ctxP, haP, hdP2);
                        const float* s1 = act_src(isAtt, c0 + c41 * 4, b1, inpT, ctxP, haP, hdP2);
                        float4 v0, v1;
                        LOAD2P_WAIT0(v0, v1, s0, s1);
                        *(float4*)&smem[b0 * ASTR + c40 * 4] = v0;
                        *(float4*)&smem[b1 * ASTR + c41 * 4] = v1;
                    } else {  // span 256
                        const int b0 = tid >> 6, c40 = tid & 63;
                        const float* s0 = act_src(isAtt, c0 + c40 * 4, b0, inpT, ctxP, haP, hdP2);
                        float4 v0;
                        LOAD1P_WAIT0(v0, s0);
                        *(float4*)&smem[b0 * ASTR + c40 * 4] = v0;
                    }
                    __syncthreads();
                    if constexpr (BF16) {
                        // same column split as fp32 path; 8B bf16 loads -> float4
                        if (span == 512) {
                            const int cA = c0, cB = c0 + 256;
                            const u16* pA0 = ((cA < bnd) ? (wih16 + rAih + cA) : (whh16 + rAhh + (cA - bnd))) + lane * 4;
                            const u16* pA1 = ((cB < bnd) ? (wih16 + rAih + cB) : (whh16 + rAhh + (cB - bnd))) + lane * 4;
                            const u16* pB0 = ((cA < bnd) ? (wih16 + rBih + cA) : (whh16 + rBhh + (cA - bnd))) + lane * 4;
                            const u16* pB1 = ((cB < bnd) ? (wih16 + rBih + cB) : (whh16 + rBhh + (cB - bnd))) + lane * 4;
                            u64 uA0, uA1, uB0, uB1;
                            LOADB4_WAIT0(uA0, uA1, uB0, uB1, pA0, pA1, pB0, pB1);
                            const float4 wA0 = bfx4(uA0), wA1 = bfx4(uA1);
                            const float4 wB0 = bfx4(uB0), wB1 = bfx4(uB1);
                            #pragma unroll
                            for (int b = 0; b < 16; ++b) {
                                const float4 a0 = *(const float4*)&smem[b * ASTR + lane * 4];
                                const float4 a1 = *(const float4*)&smem[b * ASTR + 256 + lane * 4];
                                accA[b] += dot4(wA0, a0) + dot4(wA1, a1);
                                accB[b] += dot4(wB0, a0) + dot4(wB1, a1);
                            }
                        } else {
                            const int cA = c0;
                            const u16* pA0 = ((cA < bnd) ? (wih16 + rAih + cA) : (whh16 + rAhh + (cA - bnd))) + lane * 4;
                            const u16* pB0 = ((cA < bnd) ? (wih16 + rBih + cA) : (whh16 + rBhh + (cA - bnd))) + lane * 4;
                            u64 uA0, uB0;
                            LOADB2_WAIT0(uA0, uB0, pA0, pB0);
                            const float4 wA0 = bfx4(uA0), wB0 = bfx4(uB0);
                            #pragma unroll
                            for (int b = 0; b < 16; ++b) {
                                const float4 a0 = *(const float4*)&smem[b * ASTR + lane * 4];
                                accA[b] += dot4(wA0, a0);
                                accB[b] += dot4(wB0, a0);
                            }
                        }
                    } else {
                        if (span == 512) {
                            const int cA = c0, cB = c0 + 256;
                            const float* pA0 = ((cA < bnd) ? (wih + rAih + cA) : (whh + rAhh + (cA - bnd))) + lane * 4;
                            const float* pA1 = ((cB < bnd) ? (wih + rAih + cB) : (whh + rAhh + (cB - bnd))) + lane * 4;
                            const float* pB0 = ((cA < bnd) ? (wih + rBih + cA) : (whh + rBhh + (cA - bnd))) + lane * 4;
                            const float* pB1 = ((cB < bnd) ? (wih + rBih + cB) : (whh + rBhh + (cB - bnd))) + lane * 4;
                            float4 wA0, wA1, wB0, wB1;
                            LOADW4_WAIT0(wA0, wA1, wB0, wB1, pA0, pA1, pB0, pB1);
                            #pragma unroll
                            for (int b = 0; b < 16; ++b) {
                                const float4 a0 = *(const float4*)&smem[b * ASTR + lane * 4];
                                const float4 a1 = *(const float4*)&smem[b * ASTR + 256 + lane * 4];
                                accA[b] += dot4(wA0, a0) + dot4(wA1, a1);
                                accB[b] += dot4(wB0, a0) + dot4(wB1, a1);
                            }
                        } else {
                            const int cA = c0;
                            const float* pA0 = ((cA < bnd) ? (wih + rAih + cA) : (whh + rAhh + (cA - bnd))) + lane * 4;
                            const float* pB0 = ((cA < bnd) ? (wih + rBih + cA) : (whh + rBhh + (cA - bnd))) + lane * 4;
                            float4 wA0, wB0;
                            LOADW2_WAIT0(wA0, wB0, pA0, pB0);
                            #pragma unroll
                            for (int b = 0; b < 16; ++b) {
                                const float4 a0 = *(const float4*)&smem[b * ASTR + lane * 4];
                                accA[b] += dot4(wA0, a0);
                                accB[b] += dot4(wB0, a0);
                            }
                        }
                    }
                    __syncthreads();
                }
                // ---- reduce across 64 lanes; predicated scratch write ----
                #pragma unroll
                for (int m = 1; m <= 32; m <<= 1) {
                    #pragma unroll
                    for (int b = 0; b < 16; ++b) {
                        accA[b] += __shfl_xor(accA[b], m, 64);
                        accB[b] += __shfl_xor(accB[b], m, 64);
                    }
                }
                #pragma unroll
                for (int b = 0; b < 16; ++b) {
                    if (lane == b) {
                        smem[SCR + gA * 128 + jw * 16 + b]       = accA[b];
                        smem[SCR + (gA + 2) * 128 + jw * 16 + b] = accB[b];
                    }
                }
                __syncthreads();
                if (tid < 128) {   // LSTM epilogue
                    const int b = tid >> 3, jb = tid & 7;
                    const int j = j0 + jb;
                    const float* bih = isAtt ? abih : dbih;
                    const float* bhh = isAtt ? abhh : dbhh;
                    float g4[4];
                    #pragma unroll
                    for (int g = 0; g < 4; ++g)
                        g4[g] = smem[SCR + g * 128 + jb * 16 + b]
                              + bih[g * 1024 + j] + bhh[g * 1024 + j];
                    const float ii = sigm(g4[0]), ff = sigm(g4[1]);
                    const float gg = tanh_f(g4[2]), oo = sigm(g4[3]);
                    c_reg = ff * c_reg + ii * gg;
                    float* hb = isAtt ? haC : hdW;
                    stc4(&hb[b * RNN + j], oo * tanh_f(c_reg));
                }
            }
        }
        grid_barrier(bar, gen); ++gen;

        // ================= P2: q-GEMV + conv + energies (32 tt per block) =================
        if (t < TDEC) {
            const int b2 = bid & 15, ts = bid >> 4;
            float* smemH  = smem;          // [1024]
            float* smemW  = smem + 1024;   // [62]
            float* smemWC = smem + 1104;   // [62]
            float* smemQ  = smem + 1184;   // [128]
            float* smemL  = smem + 1312;   // [32*33]
            if (tid < 512) {
                F2u v; v.u = ldc8u((const u64*)(haC + b2 * 1024) + tid);
                smemH[tid * 2] = v.f[0]; smemH[tid * 2 + 1] = v.f[1];
            } else if (tid < 574) {
                const int i = tid - 512;
                const int ix = ts * 32 - 15 + i;
                smemW[i] = (ix >= 0 && ix < 512) ? ldc4(wBf + b2 * 512 + ix) : 0.0f;
            } else if (tid < 636) {
                const int i = tid - 574;
                const int ix = ts * 32 - 15 + i;
                smemWC[i] = (ix >= 0 && ix < 512) ? ldc4(wcB + b2 * 512 + ix) : 0.0f;
            }
            __syncthreads();
            {
                const float4 h0 = *(const float4*)&smemH[lane * 4];
                const float4 h1 = *(const float4*)&smemH[lane * 4 + 256];
                const float4 h2 = *(const float4*)&smemH[lane * 4 + 512];
                const float4 h3 = *(const float4*)&smemH[lane * 4 + 768];
                #pragma unroll
                for (int fl = 0; fl < 8; ++fl) {
                    const int f = wid * 8 + fl;
                    const float* wqr = wq + (size_t)f * 1024 + lane * 4;
                    const float4 w0 = *(const float4*)(wqr);
                    const float4 w1 = *(const float4*)(wqr + 256);
                    const float4 w2 = *(const float4*)(wqr + 512);
                    const float4 w3 = *(const float4*)(wqr + 768);
                    float aq = dot4(w0, h0) + dot4(w1, h1) + dot4(w2, h2) + dot4(w3, h3);
                    #pragma unroll
                    for (int m = 1; m <= 32; m <<= 1) aq += __shfl_xor(aq, m, 64);
                    if (lane == 0) smemQ[f] = aq;
                }
            }
            __syncthreads();
            {
                const int ttl = tid >> 5, ch = tid & 31;
                const float* cwc = cw + ch * 62;
                float a = 0.0f;
                #pragma unroll
                for (int kk = 0; kk < 31; ++kk)
                    a += smemW[ttl + kk] * cwc[kk] + smemWC[ttl + kk] * cwc[31 + kk];
                smemL[ttl * 33 + ch] = a;
            }
            __syncthreads();
            {
                const int ttl = tid >> 5, fq = tid & 31;
                const int tt = ts * 32 + ttl;
                const float* lrow = smemL + ttl * 33;
                F4u pm4; pm4.v = __builtin_nontemporal_load(
                    (const f32x4*)(pmT + ((size_t)(b2 * 512 + tt)) * 128 + fq * 4));
                float pes = 0.0f;
                #pragma unroll
                for (int i = 0; i < 4; ++i) {
                    const int f = fq * 4 + i;
                    const float* lw = ldw + f * 32;
                    float pl = 0.0f;
                    #pragma unroll
                    for (int c2 = 0; c2 < 32; ++c2) pl += lrow[c2] * lw[c2];
                    const float x = smemQ[f] + pl + pm4.f[i];
                    pes += vat[f] * tanh_f(x);
                }
                stc4(peB + ((size_t)(b2 * 512 + tt)) * 32 + fq, pes);
            }
        }
        grid_barrier(bar, gen); ++gen;

        // ================= P3: softmax/ctx (blocks 0-63) + proj (64-93) =================
        if (bid < 64) {
            if (t < TDEC) {
                const int b3 = bid & 15, dq = bid >> 4;
                float* pl_ = smem;          // [512]
                float* red = smem + 512;    // [17]
                float* psm = smem + 544;    // [1024]
                if (tid < 512) {
                    const int tt = tid;
                    float4 l0, l1, l2, l3, l4, l5, l6, l7;
                    LOAD8X16_WAIT0(l0, l1, l2, l3, l4, l5, l6, l7,
                                   peB + ((size_t)(b3 * 512 + tt)) * 32);
                    float e = l0.x + l0.y + l0.z + l0.w + l1.x + l1.y + l1.z + l1.w
                            + l2.x + l2.y + l2.z + l2.w + l3.x + l3.y + l3.z + l3.w
                            + l4.x + l4.y + l4.z + l4.w + l5.x + l5.y + l5.z + l5.w
                            + l6.x + l6.y + l6.z + l6.w + l7.x + l7.y + l7.z + l7.w;
                    const float p = (tt < mlen[b3]) ? __expf(e) : 0.0f;
                    pl_[tt] = p;
                    float sred = p;
                    #pragma unroll
                    for (int m = 1; m <= 32; m <<= 1) sred += __shfl_xor(sred, m, 64);
                    if (lane == 0) red[wid] = sred;
                }
                __syncthreads();
                if (tid == 0) {
                    float d = 0.0f;
                    #pragma unroll
                    for (int w = 0; w < 8; ++w) d += red[w];
                    red[8] = 1.0f / d;
                }
                __syncthreads();
                const float rd = red[8];
                {
                    const int dl = tid & 127, part = tid >> 7;
                    const float* mr = mem + (size_t)b3 * (512 * 512) + dq * 128 + dl;
                    float a = 0.0f;
                    const int r0 = part * 64;
                    for (int r2_ = 0; r2_ < 64; ++r2_)
                        a += pl_[r0 + r2_] * __builtin_nontemporal_load(mr + (size_t)(r0 + r2_) * 512);
                    psm[dl * 8 + part] = a;
                }
                __syncthreads();
                if (tid < 128) {
                    float a = 0.0f;
                    #pragma unroll
                    for (int p2 = 0; p2 < 8; ++p2) a += psm[tid * 8 + p2];
                    stc4(&ctxC[b3 * 512 + dq * 128 + tid], a * rd);
                }
                if (dq == 0 && tid < 512) {
                    const float wn = pl_[tid] * rd;
                    stc4(&wBf[b3 * 512 + tid], wn);
                    stc4(&wcB[b3 * 512 + tid], ldc4(&wcB[b3 * 512 + tid]) + wn);
                    outAl[(size_t)b3 * (200 * 512) + (size_t)t * 512 + tid] = wn;
                }
            }
        } else if (bid < 94) {
            if (t >= 1) {
                const int jo = (bid - 64) * 8 + (wid >> 1);
                const int bh = wid & 1;
                const float* pwr = pjw + (size_t)jo * 1536 + lane * 4;
                float a[8] = {0, 0, 0, 0, 0, 0, 0, 0};
                #pragma unroll
                for (int pass = 0; pass < 6; ++pass) {
                    const int k = pass * 256 + lane * 4;
                    const float* qp[8];
                    #pragma unroll
                    for (int i = 0; i < 8; ++i) {
                        const int b = bh * 8 + i;
                        qp[i] = (pass < 4) ? (hdW + b * 1024 + k) : (ctxP + b * 512 + (k - 1024));
                    }
                    float4 c0, c1, c2, c3, c4, c5, c6, c7;
                    LOAD8P_WAIT0(c0, c1, c2, c3, c4, c5, c6, c7,
                                 qp[0], qp[1], qp[2], qp[3], qp[4], qp[5], qp[6], qp[7]);
                    const float4 w4 = *(const float4*)(pwr + pass * 256);
                    a[0] += dot4(w4, c0); a[1] += dot4(w4, c1);
                    a[2] += dot4(w4, c2); a[3] += dot4(w4, c3);
                    a[4] += dot4(w4, c4); a[5] += dot4(w4, c5);
                    a[6] += dot4(w4, c6); a[7] += dot4(w4, c7);
                }
                #pragma unroll
                for (int i = 0; i < 8; ++i)
                    #pragma unroll
                    for (int m = 1; m <= 32; m <<= 1) a[i] += __shfl_xor(a[i], m, 64);
                if (lane == 0) {
                    const int m_ = jo % 80;
                    const int u = (t - 1) * 3 + jo / 80;
                    const float bv = pjb[jo];
                    #pragma unroll
                    for (int i = 0; i < 8; ++i)
                        outMel[(size_t)(bh * 8 + i) * 48000 + m_ * 600 + u] = a[i] + bv;
                }
            }
        }
        grid_barrier(bar, gen); ++gen;
    }
}

extern "C" void kernel_launch(void* const* d_in, const int* in_sizes, int n_in,
                              void* d_out, int out_size, void* d_ws, size_t ws_size,
                              hipStream_t stream)
{
    (void)in_sizes; (void)n_in; (void)out_size;
    const float* mem  = (const float*)d_in[0];
    const float* di   = (const float*)d_in[1];
    const int*   mlen = (const int*)d_in[2];
    const float* pw1  = (const float*)d_in[3];
    const float* pw2  = (const float*)d_in[4];
    const float* awih = (const float*)d_in[5];
    const float* awhh = (const float*)d_in[6];
    const float* abih = (const float*)d_in[7];
    const float* abhh = (const float*)d_in[8];
    const float* dwih = (const float*)d_in[9];
    const float* dwhh = (const float*)d_in[10];
    const float* dbih = (const float*)d_in[11];
    const float* dbhh = (const float*)d_in[12];
    const float* wqp  = (const float*)d_in[13];
    const float* wmp  = (const float*)d_in[14];
    const float* vat  = (const float*)d_in[15];
    const float* cwp  = (const float*)d_in[16];
    const float* ldwp = (const float*)d_in[17];
    const float* pjw  = (const float*)d_in[18];
    const float* pjb  = (const float*)d_in[19];
    float* ws  = (float*)d_ws;
    float* out = (float*)d_out;

    const size_t needB = (size_t)W16_OFF * 4 + (size_t)U16_TOT * 2;
    const bool useBf16 = (ws_size >= needB);

    hipMemsetAsync(ws + HA_OFF, 0, ZLEN_F * sizeof(float), stream);
    hipLaunchKernelGGL(k_pm, dim3(512), dim3(256), 0, stream, mem, wmp, ws + PM_OFF);
    hipLaunchKernelGGL(k_prenet, dim3(200), dim3(256), 0, stream, di, pw1, pw2, ws + INP_OFF);
    if (useBf16) {
        u16* w16 = (u16*)(ws + W16_OFF);
        hipLaunchKernelGGL(k_cvt, dim3(512), dim3(256), 0, stream, awih, w16 + U16_AIH, 4096 * 768);
        hipLaunchKernelGGL(k_cvt, dim3(512), dim3(256), 0, stream, awhh, w16 + U16_AHH, 4096 * 1024);
        hipLaunchKernelGGL(k_cvt, dim3(512), dim3(256), 0, stream, dwih, w16 + U16_DIH, 4096 * 1536);
        hipLaunchKernelGGL(k_cvt, dim3(512), dim3(256), 0, stream, dwhh, w16 + U16_DHH, 4096 * 1024);
    }

    void* args[] = { (void*)&mem, (void*)&mlen, (void*)&awih, (void*)&awhh,
                     (void*)&abih, (void*)&abhh, (void*)&dwih, (void*)&dwhh,
                     (void*)&dbih, (void*)&dbhh, (void*)&wqp, (void*)&vat,
                     (void*)&cwp, (void*)&ldwp, (void*)&pjw, (void*)&pjb,
                     (void*)&ws, (void*)&out };
    if (useBf16)
        hipLaunchCooperativeKernel((const void*)k_main<1>, dim3(256), dim3(1024), args, 0, stream);
    else
        hipLaunchCooperativeKernel((const void*)k_main<0>, dim3(256), dim3(1024), args, 0, stream);
}

// Round 18
// 18413.922 us; speedup vs baseline: 1.6575x; 1.3338x over previous
//
#include <hip/hip_runtime.h>

// ---------------- problem constants ----------------
#define TDEC 200
#define NB   16
#define PRE  256
#define RNN  1024

// ---------------- ws layout (float offsets) ----------------
#define PM_OFF   0u          // pm[16][512][128]  (transposed)
#define INP_OFF  1048576u    // inp[200][16][256]
#define HA_OFF   1867776u    // h_a[2][16][1024]
#define HD_OFF   1900544u    // h_d[2][16][1024]
#define CTX_OFF  1933312u    // ctx[2][16][512]
#define WB_OFF   1949696u    // w[16][512]
#define WC_OFF   1957888u    // wcum[16][512]
#define BAR_OFF  1966080u    // barrier (576 u32 + pad to 1024)
#define PE_OFF   1967104u    // pe[16][512][32]
#define W16_OFF  2229248u    // bf16 weights (u16): aih|ahh|dih|dhh
#define ZLEN_F   99328u      // zero HA..PE start

// u16 offsets within bf16 region
#define U16_AIH  0u
#define U16_AHH  3145728u    // 4096*768
#define U16_DIH  7340032u    // + 4096*1024
#define U16_DHH  13631488u   // + 4096*1536
#define U16_TOT  17825792u   // + 4096*1024

// LDS: acts [16][520] = 8320 | gate scratch at 8320
#define ASTR 520
#define SCR  8320

typedef unsigned long long u64;
typedef unsigned short u16;
union F2u { u64 u; float f[2]; };

__device__ __forceinline__ float sigm(float x)   { return 1.0f / (1.0f + __expf(-x)); }
__device__ __forceinline__ float tanh_f(float x) { return 1.0f - 2.0f / (__expf(2.0f * x) + 1.0f); }

__device__ __forceinline__ float dot4(float4 u, float4 v) {
    return u.x * v.x + u.y * v.y + u.z * v.z + u.w * v.w;
}
// expand 4 bf16 (packed in u64) -> float4
__device__ __forceinline__ float4 bfx4(u64 v) {
    const unsigned lo = (unsigned)v, hi = (unsigned)(v >> 32);
    float4 r;
    r.x = __uint_as_float(lo << 16);
    r.y = __uint_as_float(lo & 0xffff0000u);
    r.z = __uint_as_float(hi << 16);
    r.w = __uint_as_float(hi & 0xffff0000u);
    return r;
}

__device__ __forceinline__ float ldc4(const float* p) {
    return __hip_atomic_load((float*)p, __ATOMIC_RELAXED, __HIP_MEMORY_SCOPE_AGENT);
}
__device__ __forceinline__ u64 ldc8u(const u64* p) {
    return __hip_atomic_load((u64*)p, __ATOMIC_RELAXED, __HIP_MEMORY_SCOPE_AGENT);
}
__device__ __forceinline__ void stc4(float* p, float v) {
    __hip_atomic_store(p, v, __ATOMIC_RELAXED, __HIP_MEMORY_SCOPE_AGENT);
}

#define LOAD1P_WAIT0(d0,p0) \
  asm volatile("global_load_dwordx4 %0, %1, off sc0 sc1\n\t" \
               "s_waitcnt vmcnt(0)" : "=&v"(d0) : "v"(p0) : "memory")

#define LOAD2P_WAIT0(d0,d1,p0,p1) \
  asm volatile("global_load_dwordx4 %0, %2, off sc0 sc1\n\t" \
               "global_load_dwordx4 %1, %3, off sc0 sc1\n\t" \
               "s_waitcnt vmcnt(0)" \
    : "=&v"(d0),"=&v"(d1) : "v"(p0),"v"(p1) : "memory")

// fp32 weights: 16B cached loads + drain
#define LOADW4_WAIT0(d0,d1,d2,d3,p0,p1,p2,p3) \
  asm volatile("global_load_dwordx4 %0, %4, off\n\t" \
               "global_load_dwordx4 %1, %5, off\n\t" \
               "global_load_dwordx4 %2, %6, off\n\t" \
               "global_load_dwordx4 %3, %7, off\n\t" \
               "s_waitcnt vmcnt(0)" \
    : "=&v"(d0),"=&v"(d1),"=&v"(d2),"=&v"(d3) \
    : "v"(p0),"v"(p1),"v"(p2),"v"(p3) : "memory")

#define LOADW2_WAIT0(d0,d1,p0,p1) \
  asm volatile("global_load_dwordx4 %0, %2, off\n\t" \
               "global_load_dwordx4 %1, %3, off\n\t" \
               "s_waitcnt vmcnt(0)" \
    : "=&v"(d0),"=&v"(d1) : "v"(p0),"v"(p1) : "memory")

// bf16 weights: 8B cached loads + drain
#define LOADB4_WAIT0(d0,d1,d2,d3,p0,p1,p2,p3) \
  asm volatile("global_load_dwordx2 %0, %4, off\n\t" \
               "global_load_dwordx2 %1, %5, off\n\t" \
               "global_load_dwordx2 %2, %6, off\n\t" \
               "global_load_dwordx2 %3, %7, off\n\t" \
               "s_waitcnt vmcnt(0)" \
    : "=&v"(d0),"=&v"(d1),"=&v"(d2),"=&v"(d3) \
    : "v"(p0),"v"(p1),"v"(p2),"v"(p3) : "memory")

#define LOADB2_WAIT0(d0,d1,p0,p1) \
  asm volatile("global_load_dwordx2 %0, %2, off\n\t" \
               "global_load_dwordx2 %1, %3, off\n\t" \
               "s_waitcnt vmcnt(0)" \
    : "=&v"(d0),"=&v"(d1) : "v"(p0),"v"(p1) : "memory")

#define LOAD8P_WAIT0(d0,d1,d2,d3,d4,d5,d6,d7,p0,p1,p2,p3,p4,p5,p6,p7) \
  asm volatile("global_load_dwordx4 %0, %8, off sc0 sc1\n\t" \
               "global_load_dwordx4 %1, %9, off sc0 sc1\n\t" \
               "global_load_dwordx4 %2, %10, off sc0 sc1\n\t" \
               "global_load_dwordx4 %3, %11, off sc0 sc1\n\t" \
               "global_load_dwordx4 %4, %12, off sc0 sc1\n\t" \
               "global_load_dwordx4 %5, %13, off sc0 sc1\n\t" \
               "global_load_dwordx4 %6, %14, off sc0 sc1\n\t" \
               "global_load_dwordx4 %7, %15, off sc0 sc1\n\t" \
               "s_waitcnt vmcnt(0)" \
    : "=&v"(d0),"=&v"(d1),"=&v"(d2),"=&v"(d3),"=&v"(d4),"=&v"(d5),"=&v"(d6),"=&v"(d7) \
    : "v"(p0),"v"(p1),"v"(p2),"v"(p3),"v"(p4),"v"(p5),"v"(p6),"v"(p7) : "memory")

#define LOAD8X16_WAIT0(d0,d1,d2,d3,d4,d5,d6,d7,p) \
  asm volatile("global_load_dwordx4 %0, %8, off sc0 sc1\n\t" \
               "global_load_dwordx4 %1, %8, off offset:16 sc0 sc1\n\t" \
               "global_load_dwordx4 %2, %8, off offset:32 sc0 sc1\n\t" \
               "global_load_dwordx4 %3, %8, off offset:48 sc0 sc1\n\t" \
               "global_load_dwordx4 %4, %8, off offset:64 sc0 sc1\n\t" \
               "global_load_dwordx4 %5, %8, off offset:80 sc0 sc1\n\t" \
               "global_load_dwordx4 %6, %8, off offset:96 sc0 sc1\n\t" \
               "global_load_dwordx4 %7, %8, off offset:112 sc0 sc1\n\t" \
               "s_waitcnt vmcnt(0)" \
    : "=&v"(d0),"=&v"(d1),"=&v"(d2),"=&v"(d3),"=&v"(d4),"=&v"(d5),"=&v"(d6),"=&v"(d7) \
    : "v"(p) : "memory")

// ---- relaxed monotonic 2-level grid barrier (256 blocks) ----
__device__ __forceinline__ void grid_barrier(unsigned* bar, unsigned g)
{
    asm volatile("s_waitcnt vmcnt(0)" ::: "memory");
    __syncthreads();
    if (threadIdx.x == 0) {
        const int leaf = (blockIdx.x & 15) * 32;
        const unsigned tgt = g * 16u + 15u;
        if (__hip_atomic_fetch_add(&bar[leaf], 1u, __ATOMIC_RELAXED, __HIP_MEMORY_SCOPE_AGENT) == tgt) {
            if (__hip_atomic_fetch_add(&bar[512], 1u, __ATOMIC_RELAXED, __HIP_MEMORY_SCOPE_AGENT) == tgt) {
                __hip_atomic_store(&bar[544], g + 1u, __ATOMIC_RELAXED, __HIP_MEMORY_SCOPE_AGENT);
            } else {
                while (__hip_atomic_load(&bar[544], __ATOMIC_RELAXED, __HIP_MEMORY_SCOPE_AGENT) != g + 1u)
                    __builtin_amdgcn_s_sleep(2);
            }
        } else {
            while (__hip_atomic_load(&bar[544], __ATOMIC_RELAXED, __HIP_MEMORY_SCOPE_AGENT) != g + 1u)
                __builtin_amdgcn_s_sleep(2);
        }
    }
    __syncthreads();
}

__device__ __forceinline__ const float* act_src(bool isAtt, int c, int b,
    const float* inpT, const float* ctxP, const float* haP, const float* hdP2)
{
    if (isAtt) {
        if (c < 256)  return inpT + b * 256 + c;
        if (c < 768)  return ctxP + b * 512 + (c - 256);
        return haP + b * 1024 + (c - 768);
    } else {
        if (c < 1024) return haP + b * 1024 + c;
        if (c < 1536) return ctxP + b * 512 + (c - 1024);
        return hdP2 + b * 1024 + (c - 1536);
    }
}

// ---------------- fp32 -> bf16 (RNE) converter ----------------
__global__ __launch_bounds__(256) void k_cvt(const float* __restrict__ src,
                                             u16* __restrict__ dst, int n)
{
    const int stride = gridDim.x * 256;
    for (int i = blockIdx.x * 256 + threadIdx.x; i < n; i += stride) {
        const unsigned x = __float_as_uint(src[i]);
        const unsigned r = x + 0x7fffu + ((x >> 16) & 1u);
        dst[i] = (u16)(r >> 16);
    }
}

// ---------------- precompute: pm[b][tt][f] (transposed) ----------------
__global__ __launch_bounds__(256) void k_pm(const float* __restrict__ mem,
                                            const float* __restrict__ Wm,
                                            float* __restrict__ pm)
{
    const int bid = blockIdx.x;
    const int b = bid >> 5, ch = bid & 31;
    const int tid = threadIdx.x;
    const int tt0 = ch * 16;
    __shared__ float ml[16][512];
    for (int i = tid; i < 16 * 128; i += 256) {
        const int r = i >> 7, c4 = (i & 127) * 4;
        *(float4*)&ml[r][c4] = *(const float4*)(mem + (size_t)(b * 512 + tt0 + r) * 512 + c4);
    }
    __syncthreads();
    const int f = tid & 127, th = tid >> 7;
    float acc[8] = {0, 0, 0, 0, 0, 0, 0, 0};
    const float* wr = Wm + f * 512;
    for (int d = 0; d < 512; d += 4) {
        const float4 w4 = *(const float4*)(wr + d);
        #pragma unroll
        for (int i = 0; i < 8; ++i) {
            const float4 m4 = *(const float4*)&ml[th * 8 + i][d];
            acc[i] += dot4(w4, m4);
        }
    }
    #pragma unroll
    for (int i = 0; i < 8; ++i)
        pm[((size_t)(b * 512 + tt0 + th * 8 + i)) * 128 + f] = acc[i];
}

// ---------------- precompute: prenet ----------------
__global__ __launch_bounds__(256) void k_prenet(const float* __restrict__ di,
                                                const float* __restrict__ W1,
                                                const float* __restrict__ W2,
                                                float* __restrict__ inp)
{
    const int t = blockIdx.x;
    const int tid = threadIdx.x;
    float* inpT = inp + (size_t)t * (NB * PRE);
    if (t == 0) {
        for (int i = tid; i < NB * PRE; i += 256) inpT[i] = 0.0f;
        return;
    }
    const int s = t - 1;
    __shared__ float xs[16][240];
    __shared__ float h1[16][256];
    for (int i = tid; i < 16 * 240; i += 256) {
        const int b = i / 240, j2 = i % 240;
        xs[b][j2] = di[(size_t)b * 48000 + (j2 % 80) * 600 + s * 3 + j2 / 80];
    }
    __syncthreads();
    const int j = tid;
    {
        float acc[16];
        #pragma unroll
        for (int b = 0; b < 16; ++b) acc[b] = 0.0f;
        const float* wr = W1 + j * 240;
        for (int k = 0; k < 240; k += 4) {
            const float4 w4 = *(const float4*)(wr + k);
            #pragma unroll
            for (int b = 0; b < 16; ++b) {
                const float4 x4 = *(const float4*)&xs[b][k];
                acc[b] += dot4(w4, x4);
            }
        }
        #pragma unroll
        for (int b = 0; b < 16; ++b) h1[b][j] = fmaxf(acc[b], 0.0f);
    }
    __syncthreads();
    {
        float acc[16];
        #pragma unroll
        for (int b = 0; b < 16; ++b) acc[b] = 0.0f;
        const float* wr = W2 + j * 256;
        for (int k = 0; k < 256; k += 4) {
            const float4 w4 = *(const float4*)(wr + k);
            #pragma unroll
            for (int b = 0; b < 16; ++b) {
                const float4 x4 = *(const float4*)&h1[b][k];
                acc[b] += dot4(w4, x4);
            }
        }
        #pragma unroll
        for (int b = 0; b < 16; ++b) inpT[b * 256 + j] = fmaxf(acc[b], 0.0f);
    }
}

// ---------------- persistent decoder kernel: 256 blocks x 1024 threads ----------------
template<int BF16>
__global__ __launch_bounds__(1024) void k_main(
    const float* __restrict__ mem,  const int* __restrict__ mlen,
    const float* __restrict__ awih, const float* __restrict__ awhh,
    const float* __restrict__ abih, const float* __restrict__ abhh,
    const float* __restrict__ dwih, const float* __restrict__ dwhh,
    const float* __restrict__ dbih, const float* __restrict__ dbhh,
    const float* __restrict__ wq,   const float* __restrict__ vat,
    const float* __restrict__ cw,   const float* __restrict__ ldw,
    const float* __restrict__ pjw,  const float* __restrict__ pjb,
    float* __restrict__ ws, float* __restrict__ out)
{
    const int tid  = threadIdx.x;
    const int bid  = blockIdx.x;
    const int wid  = tid >> 6;
    const int lane = tid & 63;

    float* pmT  = ws + PM_OFF;
    float* inp  = ws + INP_OFF;
    float* haB  = ws + HA_OFF;
    float* hdB  = ws + HD_OFF;
    float* ctxB = ws + CTX_OFF;
    float* wBf  = ws + WB_OFF;
    float* wcB  = ws + WC_OFF;
    float* peB  = ws + PE_OFF;
    unsigned* bar = (unsigned*)(ws + BAR_OFF);
    const u16* w16 = (const u16*)(ws + W16_OFF);
    float* outMel = out;
    float* outAl  = out + 768000;

    __shared__ float smem[8832];    // acts [16][520] + gate scratch
    unsigned gen = 0;
    float c_reg = 0.0f;             // persistent cell state, owned by tid<128

    const bool isAtt = (bid < 128);
    const int j0 = (isAtt ? bid : bid - 128) * 8;

    const float* wih = isAtt ? awih : dwih;
    const float* whh = isAtt ? awhh : dwhh;
    const u16* wih16 = w16 + (isAtt ? U16_AIH : U16_DIH);
    const u16* whh16 = w16 + (isAtt ? U16_AHH : U16_DHH);
    const int wihs = isAtt ? 768 : 1536;
    const int bnd  = wihs;
    const int K    = isAtt ? 1792 : 2560;
    const int nchk = (K + 511) >> 9;

    // wave task: gates {gA, gA+2} for row j0+jw
    const int gA = wid >> 3;
    const int jw = wid & 7;
    const int jj = j0 + jw;
    const size_t rAih = (size_t)(gA * 1024 + jj) * wihs;
    const size_t rBih = (size_t)((gA + 2) * 1024 + jj) * wihs;
    const size_t rAhh = (size_t)(gA * 1024 + jj) * 1024;
    const size_t rBhh = (size_t)((gA + 2) * 1024 + jj) * 1024;

    for (int t = 0; t <= TDEC; ++t) {
        const float* haP  = haB + ((t + 1) & 1) * (NB * RNN);
        float*       haC  = haB + (t & 1) * (NB * RNN);
        const float* hdP2 = hdB + (t & 1) * (NB * RNN);
        float*       hdW  = hdB + ((t + 1) & 1) * (NB * RNN);
        const float* ctxP = ctxB + ((t + 1) & 1) * (NB * 512);
        float*       ctxC = ctxB + (t & 1) * (NB * 512);
        const float* inpT = inp + (size_t)t * (NB * PRE);

        // ============ P1: gate GEMV — acts in LDS; weights fp32 or bf16 ============
        {
            const bool act = isAtt ? (t < TDEC) : (t >= 1);
            if (act) {
                float accA[16], accB[16];
                #pragma unroll
                for (int b = 0; b < 16; ++b) { accA[b] = 0.0f; accB[b] = 0.0f; }
                for (int chv = 0; chv < nchk; ++chv) {
                    const int c0 = chv << 9;
                    const int span = (K - c0 < 512) ? (K - c0) : 512;
                    // ---- stage acts -> LDS [b][ASTR] ----
                    if (span == 512) {
                        const int f0 = tid, f1 = tid + 1024;
                        const int b0 = f0 >> 7, c40 = f0 & 127;
                        const int b1 = f1 >> 7, c41 = f1 & 127;
                        const float* s0 = act_src(isAtt, c0 + c40 * 4, b0, inpT, ctxP, haP, hdP2);
                        const float* s1 = act_src(isAtt, c0 + c41 * 4, b1, inpT, ctxP, haP, hdP2);
                        float4 v0, v1;
                        LOAD2P_WAIT0(v0, v1, s0, s1);
                        *(float4*)&smem[b0 * ASTR + c40 * 4] = v0;
                        *(float4*)&smem[b1 * ASTR + c41 * 4] = v1;
                    } else {  // span 256
                        const int b0 = tid >> 6, c40 = tid & 63;
                        const float* s0 = act_src(isAtt, c0 + c40 * 4, b0, inpT, ctxP, haP, hdP2);
                        float4 v0;
                        LOAD1P_WAIT0(v0, s0);
                        *(float4*)&smem[b0 * ASTR + c40 * 4] = v0;
                    }
                    __syncthreads();
                    if constexpr (BF16) {
                        if (span == 512) {
                            const int cA = c0, cB = c0 + 256;
                            const u16* pA0 = ((cA < bnd) ? (wih16 + rAih + cA) : (whh16 + rAhh + (cA - bnd))) + lane * 4;
                            const u16* pA1 = ((cB < bnd) ? (wih16 + rAih + cB) : (whh16 + rAhh + (cB - bnd))) + lane * 4;
                            const u16* pB0 = ((cA < bnd) ? (wih16 + rBih + cA) : (whh16 + rBhh + (cA - bnd))) + lane * 4;
                            const u16* pB1 = ((cB < bnd) ? (wih16 + rBih + cB) : (whh16 + rBhh + (cB - bnd))) + lane * 4;
                            u64 uA0, uA1, uB0, uB1;
                            LOADB4_WAIT0(uA0, uA1, uB0, uB1, pA0, pA1, pB0, pB1);
                            const float4 wA0 = bfx4(uA0), wA1 = bfx4(uA1);
                            const float4 wB0 = bfx4(uB0), wB1 = bfx4(uB1);
                            #pragma unroll
                            for (int b = 0; b < 16; ++b) {
                                const float4 a0 = *(const float4*)&smem[b * ASTR + lane * 4];
                                const float4 a1 = *(const float4*)&smem[b * ASTR + 256 + lane * 4];
                                accA[b] += dot4(wA0, a0) + dot4(wA1, a1);
                                accB[b] += dot4(wB0, a0) + dot4(wB1, a1);
                            }
                        } else {
                            const int cA = c0;
                            const u16* pA0 = ((cA < bnd) ? (wih16 + rAih + cA) : (whh16 + rAhh + (cA - bnd))) + lane * 4;
                            const u16* pB0 = ((cA < bnd) ? (wih16 + rBih + cA) : (whh16 + rBhh + (cA - bnd))) + lane * 4;
                            u64 uA0, uB0;
                            LOADB2_WAIT0(uA0, uB0, pA0, pB0);
                            const float4 wA0 = bfx4(uA0), wB0 = bfx4(uB0);
                            #pragma unroll
                            for (int b = 0; b < 16; ++b) {
                                const float4 a0 = *(const float4*)&smem[b * ASTR + lane * 4];
                                accA[b] += dot4(wA0, a0);
                                accB[b] += dot4(wB0, a0);
                            }
                        }
                    } else {
                        if (span == 512) {
                            const int cA = c0, cB = c0 + 256;
                            const float* pA0 = ((cA < bnd) ? (wih + rAih + cA) : (whh + rAhh + (cA - bnd))) + lane * 4;
                            const float* pA1 = ((cB < bnd) ? (wih + rAih + cB) : (whh + rAhh + (cB - bnd))) + lane * 4;
                            const float* pB0 = ((cA < bnd) ? (wih + rBih + cA) : (whh + rBhh + (cA - bnd))) + lane * 4;
                            const float* pB1 = ((cB < bnd) ? (wih + rBih + cB) : (whh + rBhh + (cB - bnd))) + lane * 4;
                            float4 wA0, wA1, wB0, wB1;
                            LOADW4_WAIT0(wA0, wA1, wB0, wB1, pA0, pA1, pB0, pB1);
                            #pragma unroll
                            for (int b = 0; b < 16; ++b) {
                                const float4 a0 = *(const float4*)&smem[b * ASTR + lane * 4];
                                const float4 a1 = *(const float4*)&smem[b * ASTR + 256 + lane * 4];
                                accA[b] += dot4(wA0, a0) + dot4(wA1, a1);
                                accB[b] += dot4(wB0, a0) + dot4(wB1, a1);
                            }
                        } else {
                            const int cA = c0;
                            const float* pA0 = ((cA < bnd) ? (wih + rAih + cA) : (whh + rAhh + (cA - bnd))) + lane * 4;
                            const float* pB0 = ((cA < bnd) ? (wih + rBih + cA) : (whh + rBhh + (cA - bnd))) + lane * 4;
                            float4 wA0, wB0;
                            LOADW2_WAIT0(wA0, wB0, pA0, pB0);
                            #pragma unroll
                            for (int b = 0; b < 16; ++b) {
                                const float4 a0 = *(const float4*)&smem[b * ASTR + lane * 4];
                                accA[b] += dot4(wA0, a0);
                                accB[b] += dot4(wB0, a0);
                            }
                        }
                    }
                    __syncthreads();
                }
                // ---- reduce across 64 lanes; predicated scratch write ----
                #pragma unroll
                for (int m = 1; m <= 32; m <<= 1) {
                    #pragma unroll
                    for (int b = 0; b < 16; ++b) {
                        accA[b] += __shfl_xor(accA[b], m, 64);
                        accB[b] += __shfl_xor(accB[b], m, 64);
                    }
                }
                #pragma unroll
                for (int b = 0; b < 16; ++b) {
                    if (lane == b) {
                        smem[SCR + gA * 128 + jw * 16 + b]       = accA[b];
                        smem[SCR + (gA + 2) * 128 + jw * 16 + b] = accB[b];
                    }
                }
                __syncthreads();
                if (tid < 128) {   // LSTM epilogue
                    const int b = tid >> 3, jb = tid & 7;
                    const int j = j0 + jb;
                    const float* bih = isAtt ? abih : dbih;
                    const float* bhh = isAtt ? abhh : dbhh;
                    float g4[4];
                    #pragma unroll
                    for (int g = 0; g < 4; ++g)
                        g4[g] = smem[SCR + g * 128 + jb * 16 + b]
                              + bih[g * 1024 + j] + bhh[g * 1024 + j];
                    const float ii = sigm(g4[0]), ff = sigm(g4[1]);
                    const float gg = tanh_f(g4[2]), oo = sigm(g4[3]);
                    c_reg = ff * c_reg + ii * gg;
                    float* hb = isAtt ? haC : hdW;
                    stc4(&hb[b * RNN + j], oo * tanh_f(c_reg));
                }
            }
        }
        grid_barrier(bar, gen); ++gen;

        // ================= P2: q-GEMV + conv + energies (32 tt per block) =================
        if (t < TDEC) {
            const int b2 = bid & 15, ts = bid >> 4;
            float* smemH  = smem;          // [1024]
            float* smemW  = smem + 1024;   // [62]
            float* smemWC = smem + 1104;   // [62]
            float* smemQ  = smem + 1184;   // [128]
            float* smemL  = smem + 1312;   // [32*33]
            if (tid < 512) {
                F2u v; v.u = ldc8u((const u64*)(haC + b2 * 1024) + tid);
                smemH[tid * 2] = v.f[0]; smemH[tid * 2 + 1] = v.f[1];
            } else if (tid < 574) {
                const int i = tid - 512;
                const int ix = ts * 32 - 15 + i;
                smemW[i] = (ix >= 0 && ix < 512) ? ldc4(wBf + b2 * 512 + ix) : 0.0f;
            } else if (tid < 636) {
                const int i = tid - 574;
                const int ix = ts * 32 - 15 + i;
                smemWC[i] = (ix >= 0 && ix < 512) ? ldc4(wcB + b2 * 512 + ix) : 0.0f;
            }
            __syncthreads();
            {
                const float4 h0 = *(const float4*)&smemH[lane * 4];
                const float4 h1 = *(const float4*)&smemH[lane * 4 + 256];
                const float4 h2 = *(const float4*)&smemH[lane * 4 + 512];
                const float4 h3 = *(const float4*)&smemH[lane * 4 + 768];
                #pragma unroll
                for (int fl = 0; fl < 8; ++fl) {
                    const int f = wid * 8 + fl;
                    const float* wqr = wq + (size_t)f * 1024 + lane * 4;
                    const float4 w0 = *(const float4*)(wqr);
                    const float4 w1 = *(const float4*)(wqr + 256);
                    const float4 w2 = *(const float4*)(wqr + 512);
                    const float4 w3 = *(const float4*)(wqr + 768);
                    float aq = dot4(w0, h0) + dot4(w1, h1) + dot4(w2, h2) + dot4(w3, h3);
                    #pragma unroll
                    for (int m = 1; m <= 32; m <<= 1) aq += __shfl_xor(aq, m, 64);
                    if (lane == 0) smemQ[f] = aq;
                }
            }
            __syncthreads();
            {
                const int ttl = tid >> 5, ch = tid & 31;
                const float* cwc = cw + ch * 62;
                float a = 0.0f;
                #pragma unroll
                for (int kk = 0; kk < 31; ++kk)
                    a += smemW[ttl + kk] * cwc[kk] + smemWC[ttl + kk] * cwc[31 + kk];
                smemL[ttl * 33 + ch] = a;
            }
            __syncthreads();
            {
                const int ttl = tid >> 5, fq = tid & 31;
                const int tt = ts * 32 + ttl;
                const float* lrow = smemL + ttl * 33;
                const float4 pm4 = *(const float4*)(pmT + ((size_t)(b2 * 512 + tt)) * 128 + fq * 4);
                const float pmv[4] = {pm4.x, pm4.y, pm4.z, pm4.w};
                float pes = 0.0f;
                #pragma unroll
                for (int i = 0; i < 4; ++i) {
                    const int f = fq * 4 + i;
                    const float* lw = ldw + f * 32;
                    float pl = 0.0f;
                    #pragma unroll
                    for (int c2 = 0; c2 < 32; ++c2) pl += lrow[c2] * lw[c2];
                    const float x = smemQ[f] + pl + pmv[i];
                    pes += vat[f] * tanh_f(x);
                }
                stc4(peB + ((size_t)(b2 * 512 + tt)) * 32 + fq, pes);
            }
        }
        grid_barrier(bar, gen); ++gen;

        // ================= P3: softmax/ctx (blocks 0-63) + proj (64-93) =================
        if (bid < 64) {
            if (t < TDEC) {
                const int b3 = bid & 15, dq = bid >> 4;
                float* pl_ = smem;          // [512]
                float* red = smem + 512;    // [17]
                float* psm = smem + 544;    // [128*33]
                if (tid < 512) {
                    const int tt = tid;
                    float4 l0, l1, l2, l3, l4, l5, l6, l7;
                    LOAD8X16_WAIT0(l0, l1, l2, l3, l4, l5, l6, l7,
                                   peB + ((size_t)(b3 * 512 + tt)) * 32);
                    float e = l0.x + l0.y + l0.z + l0.w + l1.x + l1.y + l1.z + l1.w
                            + l2.x + l2.y + l2.z + l2.w + l3.x + l3.y + l3.z + l3.w
                            + l4.x + l4.y + l4.z + l4.w + l5.x + l5.y + l5.z + l5.w
                            + l6.x + l6.y + l6.z + l6.w + l7.x + l7.y + l7.z + l7.w;
                    const float p = (tt < mlen[b3]) ? __expf(e) : 0.0f;
                    pl_[tt] = p;
                    float sred = p;
                    #pragma unroll
                    for (int m = 1; m <= 32; m <<= 1) sred += __shfl_xor(sred, m, 64);
                    if (lane == 0) red[wid] = sred;
                }
                __syncthreads();
                if (tid == 0) {
                    float d = 0.0f;
                    #pragma unroll
                    for (int w = 0; w < 8; ++w) d += red[w];
                    red[8] = 1.0f / d;
                }
                __syncthreads();
                const float rd = red[8];
                {   // ctx: coalesced cached float4; thread (rg = tid>>5, c4 = tid&31)
                    const int rg = tid >> 5, c4 = tid & 31;
                    const float* mb = mem + (size_t)b3 * (512 * 512) + dq * 128 + c4 * 4;
                    float ax = 0, ay = 0, az = 0, aw = 0;
                    #pragma unroll 4
                    for (int r = 0; r < 16; ++r) {
                        const int row = rg * 16 + r;
                        const float4 m4 = *(const float4*)(mb + (size_t)row * 512);
                        const float p = pl_[row];
                        ax += p * m4.x; ay += p * m4.y; az += p * m4.z; aw += p * m4.w;
                    }
                    psm[(c4 * 4 + 0) * 33 + rg] = ax;
                    psm[(c4 * 4 + 1) * 33 + rg] = ay;
                    psm[(c4 * 4 + 2) * 33 + rg] = az;
                    psm[(c4 * 4 + 3) * 33 + rg] = aw;
                }
                __syncthreads();
                if (tid < 128) {
                    float a = 0.0f;
                    #pragma unroll
                    for (int g = 0; g < 32; ++g) a += psm[tid * 33 + g];
                    stc4(&ctxC[b3 * 512 + dq * 128 + tid], a * rd);
                }
                if (dq == 0 && tid < 512) {
                    const float wn = pl_[tid] * rd;
                    stc4(&wBf[b3 * 512 + tid], wn);
                    stc4(&wcB[b3 * 512 + tid], ldc4(&wcB[b3 * 512 + tid]) + wn);
                    outAl[(size_t)b3 * (200 * 512) + (size_t)t * 512 + tid] = wn;
                }
            }
        } else if (bid < 94) {
            if (t >= 1) {
                const int jo = (bid - 64) * 8 + (wid >> 1);
                const int bh = wid & 1;
                const float* pwr = pjw + (size_t)jo * 1536 + lane * 4;
                float a[8] = {0, 0, 0, 0, 0, 0, 0, 0};
                #pragma unroll
                for (int pass = 0; pass < 6; ++pass) {
                    const int k = pass * 256 + lane * 4;
                    const float* qp[8];
                    #pragma unroll
                    for (int i = 0; i < 8; ++i) {
                        const int b = bh * 8 + i;
                        qp[i] = (pass < 4) ? (hdW + b * 1024 + k) : (ctxP + b * 512 + (k - 1024));
                    }
                    float4 c0, c1, c2, c3, c4, c5, c6, c7;
                    LOAD8P_WAIT0(c0, c1, c2, c3, c4, c5, c6, c7,
                                 qp[0], qp[1], qp[2], qp[3], qp[4], qp[5], qp[6], qp[7]);
                    const float4 w4 = *(const float4*)(pwr + pass * 256);
                    a[0] += dot4(w4, c0); a[1] += dot4(w4, c1);
                    a[2] += dot4(w4, c2); a[3] += dot4(w4, c3);
                    a[4] += dot4(w4, c4); a[5] += dot4(w4, c5);
                    a[6] += dot4(w4, c6); a[7] += dot4(w4, c7);
                }
                #pragma unroll
                for (int i = 0; i < 8; ++i)
                    #pragma unroll
                    for (int m = 1; m <= 32; m <<= 1) a[i] += __shfl_xor(a[i], m, 64);
                if (lane == 0) {
                    const int m_ = jo % 80;
                    const int u = (t - 1) * 3 + jo / 80;
                    const float bv = pjb[jo];
                    #pragma unroll
                    for (int i = 0; i < 8; ++i)
                        outMel[(size_t)(bh * 8 + i) * 48000 + m_ * 600 + u] = a[i] + bv;
                }
            }
        }
        grid_barrier(bar, gen); ++gen;
    }
}

extern "C" void kernel_launch(void* const* d_in, const int* in_sizes, int n_in,
                              void* d_out, int out_size, void* d_ws, size_t ws_size,
                              hipStream_t stream)
{
    (void)in_sizes; (void)n_in; (void)out_size;
    const float* mem  = (const float*)d_in[0];
    const float* di   = (const float*)d_in[1];
    const int*   mlen = (const int*)d_in[2];
    const float* pw1  = (const float*)d_in[3];
    const float* pw2  = (const float*)d_in[4];
    const float* awih = (const float*)d_in[5];
    const float* awhh = (const float*)d_in[6];
    const float* abih = (const float*)d_in[7];
    const float* abhh = (const float*)d_in[8];
    const float* dwih = (const float*)d_in[9];
    const float* dwhh = (const float*)d_in[10];
    const float* dbih = (const float*)d_in[11];
    const float* dbhh = (const float*)d_in[12];
    const float* wqp  = (const float*)d_in[13];
    const float* wmp  = (const float*)d_in[14];
    const float* vat  = (const float*)d_in[15];
    const float* cwp  = (const float*)d_in[16];
    const float* ldwp = (const float*)d_in[17];
    const float* pjw  = (const float*)d_in[18];
    const float* pjb  = (const float*)d_in[19];
    float* ws  = (float*)d_ws;
    float* out = (float*)d_out;

    const size_t needB = (size_t)W16_OFF * 4 + (size_t)U16_TOT * 2;
    const bool useBf16 = (ws_size >= needB);

    hipMemsetAsync(ws + HA_OFF, 0, ZLEN_F * sizeof(float), stream);
    hipLaunchKernelGGL(k_pm, dim3(512), dim3(256), 0, stream, mem, wmp, ws + PM_OFF);
    hipLaunchKernelGGL(k_prenet, dim3(200), dim3(256), 0, stream, di, pw1, pw2, ws + INP_OFF);
    if (useBf16) {
        u16* w16 = (u16*)(ws + W16_OFF);
        hipLaunchKernelGGL(k_cvt, dim3(512), dim3(256), 0, stream, awih, w16 + U16_AIH, 4096 * 768);
        hipLaunchKernelGGL(k_cvt, dim3(512), dim3(256), 0, stream, awhh, w16 + U16_AHH, 4096 * 1024);
        hipLaunchKernelGGL(k_cvt, dim3(512), dim3(256), 0, stream, dwih, w16 + U16_DIH, 4096 * 1536);
        hipLaunchKernelGGL(k_cvt, dim3(512), dim3(256), 0, stream, dwhh, w16 + U16_DHH, 4096 * 1024);
    }

    void* args[] = { (void*)&mem, (void*)&mlen, (void*)&awih, (void*)&awhh,
                     (void*)&abih, (void*)&abhh, (void*)&dwih, (void*)&dwhh,
                     (void*)&dbih, (void*)&dbhh, (void*)&wqp, (void*)&vat,
                     (void*)&cwp, (void*)&ldwp, (void*)&pjw, (void*)&pjb,
                     (void*)&ws, (void*)&out };
    if (useBf16)
        hipLaunchCooperativeKernel((const void*)k_main<1>, dim3(256), dim3(1024), args, 0, stream);
    else
        hipLaunchCooperativeKernel((const void*)k_main<0>, dim3(256), dim3(1024), args, 0, stream);
}

// Round 19
// 17983.388 us; speedup vs baseline: 1.6972x; 1.0239x over previous
//
#include <hip/hip_runtime.h>

// ---------------- problem constants ----------------
#define TDEC 200
#define NB   16
#define PRE  256
#define RNN  1024

// ---------------- ws layout (float offsets) ----------------
#define PM_OFF   0u          // pm[16][512][128]  (transposed)
#define INP_OFF  1048576u    // inp[200][16][256]
#define HA_OFF   1867776u    // h_a[2][16][1024]
#define HD_OFF   1900544u    // h_d[2][16][1024]
#define CTX_OFF  1933312u    // ctx[2][16][512]
#define WB_OFF   1949696u    // w[16][512]
#define WC_OFF   1957888u    // wcum[16][512]
#define BAR_OFF  1966080u    // barrier (576 u32 + pad to 1024)
#define PE_OFF   1967104u    // pe[16][512][32]
#define W16_OFF  2229248u    // bf16 region (u16)
#define ZLEN_F   99328u      // zero HA..PE start

// u16 offsets within bf16 region
#define U16_AIH  0u
#define U16_AHH  3145728u    // 4096*768
#define U16_DIH  7340032u    // + 4096*1024
#define U16_DHH  13631488u   // + 4096*1536
#define U16_HA   17825792u   // ha16[2][16][1024] = 32768
#define U16_HD   17858560u   // hd16[2][16][1024] = 32768
#define U16_CTX  17891328u   // ctx16[2][16][512] = 16384
#define U16_INP  17907712u   // inp16[200][16][256] = 819200
#define U16_END  18726912u

// LDS: acts [16][520] = 8320 | gate scratch at 8320
#define ASTR 520
#define SCR  8320

typedef unsigned long long u64;
typedef unsigned short u16;
union F2u { u64 u; float f[2]; };
union F4U4 { float4 f; uint4 u; };

__device__ __forceinline__ float sigm(float x)   { return 1.0f / (1.0f + __expf(-x)); }
__device__ __forceinline__ float tanh_f(float x) { return 1.0f - 2.0f / (__expf(2.0f * x) + 1.0f); }

__device__ __forceinline__ float dot4(float4 u, float4 v) {
    return u.x * v.x + u.y * v.y + u.z * v.z + u.w * v.w;
}
__device__ __forceinline__ float4 bfx4(u64 v) {
    const unsigned lo = (unsigned)v, hi = (unsigned)(v >> 32);
    float4 r;
    r.x = __uint_as_float(lo << 16);
    r.y = __uint_as_float(lo & 0xffff0000u);
    r.z = __uint_as_float(hi << 16);
    r.w = __uint_as_float(hi & 0xffff0000u);
    return r;
}
__device__ __forceinline__ u16 tob16(float f) {
    const unsigned x = __float_as_uint(f);
    return (u16)((x + 0x7fffu + ((x >> 16) & 1u)) >> 16);
}

__device__ __forceinline__ float ldc4(const float* p) {
    return __hip_atomic_load((float*)p, __ATOMIC_RELAXED, __HIP_MEMORY_SCOPE_AGENT);
}
__device__ __forceinline__ u64 ldc8u(const u64* p) {
    return __hip_atomic_load((u64*)p, __ATOMIC_RELAXED, __HIP_MEMORY_SCOPE_AGENT);
}
__device__ __forceinline__ void stc4(float* p, float v) {
    __hip_atomic_store(p, v, __ATOMIC_RELAXED, __HIP_MEMORY_SCOPE_AGENT);
}
__device__ __forceinline__ void stc2u(u16* p, u16 v) {
    __hip_atomic_store(p, v, __ATOMIC_RELAXED, __HIP_MEMORY_SCOPE_AGENT);
}

#define LOAD1P_WAIT0(d0,p0) \
  asm volatile("global_load_dwordx4 %0, %1, off sc0 sc1\n\t" \
               "s_waitcnt vmcnt(0)" : "=&v"(d0) : "v"(p0) : "memory")

#define LOAD2P_WAIT0(d0,d1,p0,p1) \
  asm volatile("global_load_dwordx4 %0, %2, off sc0 sc1\n\t" \
               "global_load_dwordx4 %1, %3, off sc0 sc1\n\t" \
               "s_waitcnt vmcnt(0)" \
    : "=&v"(d0),"=&v"(d1) : "v"(p0),"v"(p1) : "memory")

// fp32 weights (fallback): 16B cached loads + drain
#define LOADW4_WAIT0(d0,d1,d2,d3,p0,p1,p2,p3) \
  asm volatile("global_load_dwordx4 %0, %4, off\n\t" \
               "global_load_dwordx4 %1, %5, off\n\t" \
               "global_load_dwordx4 %2, %6, off\n\t" \
               "global_load_dwordx4 %3, %7, off\n\t" \
               "s_waitcnt vmcnt(0)" \
    : "=&v"(d0),"=&v"(d1),"=&v"(d2),"=&v"(d3) \
    : "v"(p0),"v"(p1),"v"(p2),"v"(p3) : "memory")

#define LOADW2_WAIT0(d0,d1,p0,p1) \
  asm volatile("global_load_dwordx4 %0, %2, off\n\t" \
               "global_load_dwordx4 %1, %3, off\n\t" \
               "s_waitcnt vmcnt(0)" \
    : "=&v"(d0),"=&v"(d1) : "v"(p0),"v"(p1) : "memory")

// bf16 weights: 8B cached loads + drain
#define LOADB4_WAIT0(d0,d1,d2,d3,p0,p1,p2,p3) \
  asm volatile("global_load_dwordx2 %0, %4, off\n\t" \
               "global_load_dwordx2 %1, %5, off\n\t" \
               "global_load_dwordx2 %2, %6, off\n\t" \
               "global_load_dwordx2 %3, %7, off\n\t" \
               "s_waitcnt vmcnt(0)" \
    : "=&v"(d0),"=&v"(d1),"=&v"(d2),"=&v"(d3) \
    : "v"(p0),"v"(p1),"v"(p2),"v"(p3) : "memory")

#define LOADB2_WAIT0(d0,d1,p0,p1) \
  asm volatile("global_load_dwordx2 %0, %2, off\n\t" \
               "global_load_dwordx2 %1, %3, off\n\t" \
               "s_waitcnt vmcnt(0)" \
    : "=&v"(d0),"=&v"(d1) : "v"(p0),"v"(p1) : "memory")

#define LOAD8P_WAIT0(d0,d1,d2,d3,d4,d5,d6,d7,p0,p1,p2,p3,p4,p5,p6,p7) \
  asm volatile("global_load_dwordx4 %0, %8, off sc0 sc1\n\t" \
               "global_load_dwordx4 %1, %9, off sc0 sc1\n\t" \
               "global_load_dwordx4 %2, %10, off sc0 sc1\n\t" \
               "global_load_dwordx4 %3, %11, off sc0 sc1\n\t" \
               "global_load_dwordx4 %4, %12, off sc0 sc1\n\t" \
               "global_load_dwordx4 %5, %13, off sc0 sc1\n\t" \
               "global_load_dwordx4 %6, %14, off sc0 sc1\n\t" \
               "global_load_dwordx4 %7, %15, off sc0 sc1\n\t" \
               "s_waitcnt vmcnt(0)" \
    : "=&v"(d0),"=&v"(d1),"=&v"(d2),"=&v"(d3),"=&v"(d4),"=&v"(d5),"=&v"(d6),"=&v"(d7) \
    : "v"(p0),"v"(p1),"v"(p2),"v"(p3),"v"(p4),"v"(p5),"v"(p6),"v"(p7) : "memory")

#define LOAD8X16_WAIT0(d0,d1,d2,d3,d4,d5,d6,d7,p) \
  asm volatile("global_load_dwordx4 %0, %8, off sc0 sc1\n\t" \
               "global_load_dwordx4 %1, %8, off offset:16 sc0 sc1\n\t" \
               "global_load_dwordx4 %2, %8, off offset:32 sc0 sc1\n\t" \
               "global_load_dwordx4 %3, %8, off offset:48 sc0 sc1\n\t" \
               "global_load_dwordx4 %4, %8, off offset:64 sc0 sc1\n\t" \
               "global_load_dwordx4 %5, %8, off offset:80 sc0 sc1\n\t" \
               "global_load_dwordx4 %6, %8, off offset:96 sc0 sc1\n\t" \
               "global_load_dwordx4 %7, %8, off offset:112 sc0 sc1\n\t" \
               "s_waitcnt vmcnt(0)" \
    : "=&v"(d0),"=&v"(d1),"=&v"(d2),"=&v"(d3),"=&v"(d4),"=&v"(d5),"=&v"(d6),"=&v"(d7) \
    : "v"(p) : "memory")

// ---- relaxed monotonic 2-level grid barrier (256 blocks) ----
__device__ __forceinline__ void grid_barrier(unsigned* bar, unsigned g)
{
    asm volatile("s_waitcnt vmcnt(0)" ::: "memory");
    __syncthreads();
    if (threadIdx.x == 0) {
        const int leaf = (blockIdx.x & 15) * 32;
        const unsigned tgt = g * 16u + 15u;
        if (__hip_atomic_fetch_add(&bar[leaf], 1u, __ATOMIC_RELAXED, __HIP_MEMORY_SCOPE_AGENT) == tgt) {
            if (__hip_atomic_fetch_add(&bar[512], 1u, __ATOMIC_RELAXED, __HIP_MEMORY_SCOPE_AGENT) == tgt) {
                __hip_atomic_store(&bar[544], g + 1u, __ATOMIC_RELAXED, __HIP_MEMORY_SCOPE_AGENT);
            } else {
                while (__hip_atomic_load(&bar[544], __ATOMIC_RELAXED, __HIP_MEMORY_SCOPE_AGENT) != g + 1u)
                    __builtin_amdgcn_s_sleep(2);
            }
        } else {
            while (__hip_atomic_load(&bar[544], __ATOMIC_RELAXED, __HIP_MEMORY_SCOPE_AGENT) != g + 1u)
                __builtin_amdgcn_s_sleep(2);
        }
    }
    __syncthreads();
}

__device__ __forceinline__ const float* act_src(bool isAtt, int c, int b,
    const float* inpT, const float* ctxP, const float* haP, const float* hdP2)
{
    if (isAtt) {
        if (c < 256)  return inpT + b * 256 + c;
        if (c < 768)  return ctxP + b * 512 + (c - 256);
        return haP + b * 1024 + (c - 768);
    } else {
        if (c < 1024) return haP + b * 1024 + c;
        if (c < 1536) return ctxP + b * 512 + (c - 1024);
        return hdP2 + b * 1024 + (c - 1536);
    }
}

__device__ __forceinline__ const u16* act_src16(bool isAtt, int c, int b,
    const u16* i16T, const u16* c16P, const u16* h16P, const u16* h16D2)
{
    if (isAtt) {
        if (c < 256)  return i16T + b * 256 + c;
        if (c < 768)  return c16P + b * 512 + (c - 256);
        return h16P + b * 1024 + (c - 768);
    } else {
        if (c < 1024) return h16P + b * 1024 + c;
        if (c < 1536) return c16P + b * 512 + (c - 1024);
        return h16D2 + b * 1024 + (c - 1536);
    }
}

// ---------------- fp32 -> bf16 (RNE) converter ----------------
__global__ __launch_bounds__(256) void k_cvt(const float* __restrict__ src,
                                             u16* __restrict__ dst, int n)
{
    const int stride = gridDim.x * 256;
    for (int i = blockIdx.x * 256 + threadIdx.x; i < n; i += stride) {
        const unsigned x = __float_as_uint(src[i]);
        const unsigned r = x + 0x7fffu + ((x >> 16) & 1u);
        dst[i] = (u16)(r >> 16);
    }
}

// ---------------- precompute: pm[b][tt][f] (transposed) ----------------
__global__ __launch_bounds__(256) void k_pm(const float* __restrict__ mem,
                                            const float* __restrict__ Wm,
                                            float* __restrict__ pm)
{
    const int bid = blockIdx.x;
    const int b = bid >> 5, ch = bid & 31;
    const int tid = threadIdx.x;
    const int tt0 = ch * 16;
    __shared__ float ml[16][512];
    for (int i = tid; i < 16 * 128; i += 256) {
        const int r = i >> 7, c4 = (i & 127) * 4;
        *(float4*)&ml[r][c4] = *(const float4*)(mem + (size_t)(b * 512 + tt0 + r) * 512 + c4);
    }
    __syncthreads();
    const int f = tid & 127, th = tid >> 7;
    float acc[8] = {0, 0, 0, 0, 0, 0, 0, 0};
    const float* wr = Wm + f * 512;
    for (int d = 0; d < 512; d += 4) {
        const float4 w4 = *(const float4*)(wr + d);
        #pragma unroll
        for (int i = 0; i < 8; ++i) {
            const float4 m4 = *(const float4*)&ml[th * 8 + i][d];
            acc[i] += dot4(w4, m4);
        }
    }
    #pragma unroll
    for (int i = 0; i < 8; ++i)
        pm[((size_t)(b * 512 + tt0 + th * 8 + i)) * 128 + f] = acc[i];
}

// ---------------- precompute: prenet ----------------
__global__ __launch_bounds__(256) void k_prenet(const float* __restrict__ di,
                                                const float* __restrict__ W1,
                                                const float* __restrict__ W2,
                                                float* __restrict__ inp)
{
    const int t = blockIdx.x;
    const int tid = threadIdx.x;
    float* inpT = inp + (size_t)t * (NB * PRE);
    if (t == 0) {
        for (int i = tid; i < NB * PRE; i += 256) inpT[i] = 0.0f;
        return;
    }
    const int s = t - 1;
    __shared__ float xs[16][240];
    __shared__ float h1[16][256];
    for (int i = tid; i < 16 * 240; i += 256) {
        const int b = i / 240, j2 = i % 240;
        xs[b][j2] = di[(size_t)b * 48000 + (j2 % 80) * 600 + s * 3 + j2 / 80];
    }
    __syncthreads();
    const int j = tid;
    {
        float acc[16];
        #pragma unroll
        for (int b = 0; b < 16; ++b) acc[b] = 0.0f;
        const float* wr = W1 + j * 240;
        for (int k = 0; k < 240; k += 4) {
            const float4 w4 = *(const float4*)(wr + k);
            #pragma unroll
            for (int b = 0; b < 16; ++b) {
                const float4 x4 = *(const float4*)&xs[b][k];
                acc[b] += dot4(w4, x4);
            }
        }
        #pragma unroll
        for (int b = 0; b < 16; ++b) h1[b][j] = fmaxf(acc[b], 0.0f);
    }
    __syncthreads();
    {
        float acc[16];
        #pragma unroll
        for (int b = 0; b < 16; ++b) acc[b] = 0.0f;
        const float* wr = W2 + j * 256;
        for (int k = 0; k < 256; k += 4) {
            const float4 w4 = *(const float4*)(wr + k);
            #pragma unroll
            for (int b = 0; b < 16; ++b) {
                const float4 x4 = *(const float4*)&h1[b][k];
                acc[b] += dot4(w4, x4);
            }
        }
        #pragma unroll
        for (int b = 0; b < 16; ++b) inpT[b * 256 + j] = fmaxf(acc[b], 0.0f);
    }
}

// ---------------- persistent decoder kernel: 256 blocks x 1024 threads ----------------
template<int BF16>
__global__ __launch_bounds__(1024) void k_main(
    const float* __restrict__ mem,  const int* __restrict__ mlen,
    const float* __restrict__ awih, const float* __restrict__ awhh,
    const float* __restrict__ abih, const float* __restrict__ abhh,
    const float* __restrict__ dwih, const float* __restrict__ dwhh,
    const float* __restrict__ dbih, const float* __restrict__ dbhh,
    const float* __restrict__ wq,   const float* __restrict__ vat,
    const float* __restrict__ cw,   const float* __restrict__ ldw,
    const float* __restrict__ pjw,  const float* __restrict__ pjb,
    float* __restrict__ ws, float* __restrict__ out)
{
    const int tid  = threadIdx.x;
    const int bid  = blockIdx.x;
    const int wid  = tid >> 6;
    const int lane = tid & 63;

    float* pmT  = ws + PM_OFF;
    float* inp  = ws + INP_OFF;
    float* haB  = ws + HA_OFF;
    float* hdB  = ws + HD_OFF;
    float* ctxB = ws + CTX_OFF;
    float* wBf  = ws + WB_OFF;
    float* wcB  = ws + WC_OFF;
    float* peB  = ws + PE_OFF;
    unsigned* bar = (unsigned*)(ws + BAR_OFF);
    u16* w16 = (u16*)(ws + W16_OFF);
    float* outMel = out;
    float* outAl  = out + 768000;

    __shared__ float smem[8832];    // acts [16][520] + gate scratch
    unsigned gen = 0;
    float c_reg = 0.0f;             // persistent cell state, owned by tid<128

    const bool isAtt = (bid < 128);
    const int j0 = (isAtt ? bid : bid - 128) * 8;

    const float* wih = isAtt ? awih : dwih;
    const float* whh = isAtt ? awhh : dwhh;
    const u16* wih16 = w16 + (isAtt ? U16_AIH : U16_DIH);
    const u16* whh16 = w16 + (isAtt ? U16_AHH : U16_DHH);
    const int wihs = isAtt ? 768 : 1536;
    const int bnd  = wihs;
    const int K    = isAtt ? 1792 : 2560;
    const int nchk = (K + 511) >> 9;

    // wave task: gates {gA, gA+2} for row j0+jw
    const int gA = wid >> 3;
    const int jw = wid & 7;
    const int jj = j0 + jw;
    const size_t rAih = (size_t)(gA * 1024 + jj) * wihs;
    const size_t rBih = (size_t)((gA + 2) * 1024 + jj) * wihs;
    const size_t rAhh = (size_t)(gA * 1024 + jj) * 1024;
    const size_t rBhh = (size_t)((gA + 2) * 1024 + jj) * 1024;

    for (int t = 0; t <= TDEC; ++t) {
        const float* haP  = haB + ((t + 1) & 1) * (NB * RNN);
        float*       haC  = haB + (t & 1) * (NB * RNN);
        const float* hdP2 = hdB + (t & 1) * (NB * RNN);
        float*       hdW  = hdB + ((t + 1) & 1) * (NB * RNN);
        const float* ctxP = ctxB + ((t + 1) & 1) * (NB * 512);
        float*       ctxC = ctxB + (t & 1) * (NB * 512);
        const float* inpT = inp + (size_t)t * (NB * PRE);
        // bf16 shadows
        const u16* h16P  = w16 + U16_HA + ((t + 1) & 1) * 16384;
        u16*       h16C  = w16 + U16_HA + (t & 1) * 16384;
        const u16* h16D2 = w16 + U16_HD + (t & 1) * 16384;
        u16*       h16DW = w16 + U16_HD + ((t + 1) & 1) * 16384;
        const u16* c16P  = w16 + U16_CTX + ((t + 1) & 1) * 8192;
        u16*       c16C  = w16 + U16_CTX + (t & 1) * 8192;
        const u16* i16T  = w16 + U16_INP + t * 4096;

        // ============ P1: gate GEMV — acts in LDS; weights fp32 or bf16 ============
        {
            const bool act = isAtt ? (t < TDEC) : (t >= 1);
            if (act) {
                float accA[16], accB[16];
                #pragma unroll
                for (int b = 0; b < 16; ++b) { accA[b] = 0.0f; accB[b] = 0.0f; }
                for (int chv = 0; chv < nchk; ++chv) {
                    const int c0 = chv << 9;
                    const int span = (K - c0 < 512) ? (K - c0) : 512;
                    // ---- stage acts -> LDS [b][ASTR] ----
                    if constexpr (BF16) {
                        if (span == 512) {
                            const int b0 = tid >> 6, c8 = tid & 63;
                            const u16* s0 = act_src16(isAtt, c0 + c8 * 8, b0, i16T, c16P, h16P, h16D2);
                            F4U4 v; 
                            LOAD1P_WAIT0(v.f, s0);
                            const u64 lo = ((u64)v.u.y << 32) | v.u.x;
                            const u64 hi = ((u64)v.u.w << 32) | v.u.z;
                            *(float4*)&smem[b0 * ASTR + c8 * 8]     = bfx4(lo);
                            *(float4*)&smem[b0 * ASTR + c8 * 8 + 4] = bfx4(hi);
                        } else if (tid < 512) {
                            const int b0 = tid >> 5, c8 = tid & 31;
                            const u16* s0 = act_src16(isAtt, c0 + c8 * 8, b0, i16T, c16P, h16P, h16D2);
                            F4U4 v;
                            LOAD1P_WAIT0(v.f, s0);
                            const u64 lo = ((u64)v.u.y << 32) | v.u.x;
                            const u64 hi = ((u64)v.u.w << 32) | v.u.z;
                            *(float4*)&smem[b0 * ASTR + c8 * 8]     = bfx4(lo);
                            *(float4*)&smem[b0 * ASTR + c8 * 8 + 4] = bfx4(hi);
                        }
                    } else {
                        if (span == 512) {
                            const int b0 = tid >> 7, c40 = tid & 127;
                            const int b1 = (tid + 1024) >> 7, c41 = (tid + 1024) & 127;
                            const float* s0 = act_src(isAtt, c0 + c40 * 4, b0, inpT, ctxP, haP, hdP2);
                            const float* s1 = act_src(isAtt, c0 + c41 * 4, b1, inpT, ctxP, haP, hdP2);
                            float4 v0, v1;
                            LOAD2P_WAIT0(v0, v1, s0, s1);
                            *(float4*)&smem[b0 * ASTR + c40 * 4] = v0;
                            *(float4*)&smem[b1 * ASTR + c41 * 4] = v1;
                        } else {
                            const int b0 = tid >> 6, c40 = tid & 63;
                            const float* s0 = act_src(isAtt, c0 + c40 * 4, b0, inpT, ctxP, haP, hdP2);
                            float4 v0;
                            LOAD1P_WAIT0(v0, s0);
                            *(float4*)&smem[b0 * ASTR + c40 * 4] = v0;
                        }
                    }
                    __syncthreads();
                    if constexpr (BF16) {
                        if (span == 512) {
                            const int cA = c0, cB = c0 + 256;
                            const u16* pA0 = ((cA < bnd) ? (wih16 + rAih + cA) : (whh16 + rAhh + (cA - bnd))) + lane * 4;
                            const u16* pA1 = ((cB < bnd) ? (wih16 + rAih + cB) : (whh16 + rAhh + (cB - bnd))) + lane * 4;
                            const u16* pB0 = ((cA < bnd) ? (wih16 + rBih + cA) : (whh16 + rBhh + (cA - bnd))) + lane * 4;
                            const u16* pB1 = ((cB < bnd) ? (wih16 + rBih + cB) : (whh16 + rBhh + (cB - bnd))) + lane * 4;
                            u64 uA0, uA1, uB0, uB1;
                            LOADB4_WAIT0(uA0, uA1, uB0, uB1, pA0, pA1, pB0, pB1);
                            const float4 wA0 = bfx4(uA0), wA1 = bfx4(uA1);
                            const float4 wB0 = bfx4(uB0), wB1 = bfx4(uB1);
                            #pragma unroll
                            for (int b = 0; b < 16; ++b) {
                                const float4 a0 = *(const float4*)&smem[b * ASTR + lane * 4];
                                const float4 a1 = *(const float4*)&smem[b * ASTR + 256 + lane * 4];
                                accA[b] += dot4(wA0, a0) + dot4(wA1, a1);
                                accB[b] += dot4(wB0, a0) + dot4(wB1, a1);
                            }
                        } else {
                            const int cA = c0;
                            const u16* pA0 = ((cA < bnd) ? (wih16 + rAih + cA) : (whh16 + rAhh + (cA - bnd))) + lane * 4;
                            const u16* pB0 = ((cA < bnd) ? (wih16 + rBih + cA) : (whh16 + rBhh + (cA - bnd))) + lane * 4;
                            u64 uA0, uB0;
                            LOADB2_WAIT0(uA0, uB0, pA0, pB0);
                            const float4 wA0 = bfx4(uA0), wB0 = bfx4(uB0);
                            #pragma unroll
                            for (int b = 0; b < 16; ++b) {
                                const float4 a0 = *(const float4*)&smem[b * ASTR + lane * 4];
                                accA[b] += dot4(wA0, a0);
                                accB[b] += dot4(wB0, a0);
                            }
                        }
                    } else {
                        if (span == 512) {
                            const int cA = c0, cB = c0 + 256;
                            const float* pA0 = ((cA < bnd) ? (wih + rAih + cA) : (whh + rAhh + (cA - bnd))) + lane * 4;
                            const float* pA1 = ((cB < bnd) ? (wih + rAih + cB) : (whh + rAhh + (cB - bnd))) + lane * 4;
                            const float* pB0 = ((cA < bnd) ? (wih + rBih + cA) : (whh + rBhh + (cA - bnd))) + lane * 4;
                            const float* pB1 = ((cB < bnd) ? (wih + rBih + cB) : (whh + rBhh + (cB - bnd))) + lane * 4;
                            float4 wA0, wA1, wB0, wB1;
                            LOADW4_WAIT0(wA0, wA1, wB0, wB1, pA0, pA1, pB0, pB1);
                            #pragma unroll
                            for (int b = 0; b < 16; ++b) {
                                const float4 a0 = *(const float4*)&smem[b * ASTR + lane * 4];
                                const float4 a1 = *(const float4*)&smem[b * ASTR + 256 + lane * 4];
                                accA[b] += dot4(wA0, a0) + dot4(wA1, a1);
                                accB[b] += dot4(wB0, a0) + dot4(wB1, a1);
                            }
                        } else {
                            const int cA = c0;
                            const float* pA0 = ((cA < bnd) ? (wih + rAih + cA) : (whh + rAhh + (cA - bnd))) + lane * 4;
                            const float* pB0 = ((cA < bnd) ? (wih + rBih + cA) : (whh + rBhh + (cA - bnd))) + lane * 4;
                            float4 wA0, wB0;
                            LOADW2_WAIT0(wA0, wB0, pA0, pB0);
                            #pragma unroll
                            for (int b = 0; b < 16; ++b) {
                                const float4 a0 = *(const float4*)&smem[b * ASTR + lane * 4];
                                accA[b] += dot4(wA0, a0);
                                accB[b] += dot4(wB0, a0);
                            }
                        }
                    }
                    __syncthreads();
                }
                // ---- reduce across 64 lanes; predicated scratch write ----
                #pragma unroll
                for (int m = 1; m <= 32; m <<= 1) {
                    #pragma unroll
                    for (int b = 0; b < 16; ++b) {
                        accA[b] += __shfl_xor(accA[b], m, 64);
                        accB[b] += __shfl_xor(accB[b], m, 64);
                    }
                }
                #pragma unroll
                for (int b = 0; b < 16; ++b) {
                    if (lane == b) {
                        smem[SCR + gA * 128 + jw * 16 + b]       = accA[b];
                        smem[SCR + (gA + 2) * 128 + jw * 16 + b] = accB[b];
                    }
                }
                __syncthreads();
                if (tid < 128) {   // LSTM epilogue
                    const int b = tid >> 3, jb = tid & 7;
                    const int j = j0 + jb;
                    const float* bih = isAtt ? abih : dbih;
                    const float* bhh = isAtt ? abhh : dbhh;
                    float g4[4];
                    #pragma unroll
                    for (int g = 0; g < 4; ++g)
                        g4[g] = smem[SCR + g * 128 + jb * 16 + b]
                              + bih[g * 1024 + j] + bhh[g * 1024 + j];
                    const float ii = sigm(g4[0]), ff = sigm(g4[1]);
                    const float gg = tanh_f(g4[2]), oo = sigm(g4[3]);
                    c_reg = ff * c_reg + ii * gg;
                    const float h = oo * tanh_f(c_reg);
                    float* hb = isAtt ? haC : hdW;
                    stc4(&hb[b * RNN + j], h);
                    if constexpr (BF16) {
                        u16* hb16 = isAtt ? h16C : h16DW;
                        stc2u(&hb16[b * RNN + j], tob16(h));
                    }
                }
            }
        }
        grid_barrier(bar, gen); ++gen;

        // ================= P2: q-GEMV + conv + energies (32 tt per block) =================
        if (t < TDEC) {
            const int b2 = bid & 15, ts = bid >> 4;
            float* smemH  = smem;          // [1024]
            float* smemW  = smem + 1024;   // [62]
            float* smemWC = smem + 1104;   // [62]
            float* smemQ  = smem + 1184;   // [128]
            float* smemL  = smem + 1312;   // [32*33]
            if (tid < 512) {
                F2u v; v.u = ldc8u((const u64*)(haC + b2 * 1024) + tid);
                smemH[tid * 2] = v.f[0]; smemH[tid * 2 + 1] = v.f[1];
            } else if (tid < 574) {
                const int i = tid - 512;
                const int ix = ts * 32 - 15 + i;
                smemW[i] = (ix >= 0 && ix < 512) ? ldc4(wBf + b2 * 512 + ix) : 0.0f;
            } else if (tid < 636) {
                const int i = tid - 574;
                const int ix = ts * 32 - 15 + i;
                smemWC[i] = (ix >= 0 && ix < 512) ? ldc4(wcB + b2 * 512 + ix) : 0.0f;
            }
            __syncthreads();
            {
                const float4 h0 = *(const float4*)&smemH[lane * 4];
                const float4 h1 = *(const float4*)&smemH[lane * 4 + 256];
                const float4 h2 = *(const float4*)&smemH[lane * 4 + 512];
                const float4 h3 = *(const float4*)&smemH[lane * 4 + 768];
                #pragma unroll
                for (int fl = 0; fl < 8; ++fl) {
                    const int f = wid * 8 + fl;
                    const float* wqr = wq + (size_t)f * 1024 + lane * 4;
                    const float4 w0 = *(const float4*)(wqr);
                    const float4 w1 = *(const float4*)(wqr + 256);
                    const float4 w2 = *(const float4*)(wqr + 512);
                    const float4 w3 = *(const float4*)(wqr + 768);
                    float aq = dot4(w0, h0) + dot4(w1, h1) + dot4(w2, h2) + dot4(w3, h3);
                    #pragma unroll
                    for (int m = 1; m <= 32; m <<= 1) aq += __shfl_xor(aq, m, 64);
                    if (lane == 0) smemQ[f] = aq;
                }
            }
            __syncthreads();
            {
                const int ttl = tid >> 5, ch = tid & 31;
                const float* cwc = cw + ch * 62;
                float a = 0.0f;
                #pragma unroll
                for (int kk = 0; kk < 31; ++kk)
                    a += smemW[ttl + kk] * cwc[kk] + smemWC[ttl + kk] * cwc[31 + kk];
                smemL[ttl * 33 + ch] = a;
            }
            __syncthreads();
            {
                const int ttl = tid >> 5, fq = tid & 31;
                const int tt = ts * 32 + ttl;
                const float* lrow = smemL + ttl * 33;
                const float4 pm4 = *(const float4*)(pmT + ((size_t)(b2 * 512 + tt)) * 128 + fq * 4);
                const float pmv[4] = {pm4.x, pm4.y, pm4.z, pm4.w};
                float pes = 0.0f;
                #pragma unroll
                for (int i = 0; i < 4; ++i) {
                    const int f = fq * 4 + i;
                    const float* lw = ldw + f * 32;
                    float pl = 0.0f;
                    #pragma unroll
                    for (int c2 = 0; c2 < 32; ++c2) pl += lrow[c2] * lw[c2];
                    const float x = smemQ[f] + pl + pmv[i];
                    pes += vat[f] * tanh_f(x);
                }
                stc4(peB + ((size_t)(b2 * 512 + tt)) * 32 + fq, pes);
            }
        }
        grid_barrier(bar, gen); ++gen;

        // ================= P3: softmax/ctx (blocks 0-63) + proj (64-93) =================
        if (bid < 64) {
            if (t < TDEC) {
                const int b3 = bid & 15, dq = bid >> 4;
                float* pl_ = smem;          // [512]
                float* red = smem + 512;    // [17]
                float* psm = smem + 544;    // [128*33]
                if (tid < 512) {
                    const int tt = tid;
                    float4 l0, l1, l2, l3, l4, l5, l6, l7;
                    LOAD8X16_WAIT0(l0, l1, l2, l3, l4, l5, l6, l7,
                                   peB + ((size_t)(b3 * 512 + tt)) * 32);
                    float e = l0.x + l0.y + l0.z + l0.w + l1.x + l1.y + l1.z + l1.w
                            + l2.x + l2.y + l2.z + l2.w + l3.x + l3.y + l3.z + l3.w
                            + l4.x + l4.y + l4.z + l4.w + l5.x + l5.y + l5.z + l5.w
                            + l6.x + l6.y + l6.z + l6.w + l7.x + l7.y + l7.z + l7.w;
                    const float p = (tt < mlen[b3]) ? __expf(e) : 0.0f;
                    pl_[tt] = p;
                    float sred = p;
                    #pragma unroll
                    for (int m = 1; m <= 32; m <<= 1) sred += __shfl_xor(sred, m, 64);
                    if (lane == 0) red[wid] = sred;
                }
                __syncthreads();
                if (tid == 0) {
                    float d = 0.0f;
                    #pragma unroll
                    for (int w = 0; w < 8; ++w) d += red[w];
                    red[8] = 1.0f / d;
                }
                __syncthreads();
                const float rd = red[8];
                {   // ctx: coalesced cached float4
                    const int rg = tid >> 5, c4 = tid & 31;
                    const float* mb = mem + (size_t)b3 * (512 * 512) + dq * 128 + c4 * 4;
                    float ax = 0, ay = 0, az = 0, aw = 0;
                    #pragma unroll 4
                    for (int r = 0; r < 16; ++r) {
                        const int row = rg * 16 + r;
                        const float4 m4 = *(const float4*)(mb + (size_t)row * 512);
                        const float p = pl_[row];
                        ax += p * m4.x; ay += p * m4.y; az += p * m4.z; aw += p * m4.w;
                    }
                    psm[(c4 * 4 + 0) * 33 + rg] = ax;
                    psm[(c4 * 4 + 1) * 33 + rg] = ay;
                    psm[(c4 * 4 + 2) * 33 + rg] = az;
                    psm[(c4 * 4 + 3) * 33 + rg] = aw;
                }
                __syncthreads();
                if (tid < 128) {
                    float a = 0.0f;
                    #pragma unroll
                    for (int g = 0; g < 32; ++g) a += psm[tid * 33 + g];
                    const float cv = a * rd;
                    stc4(&ctxC[b3 * 512 + dq * 128 + tid], cv);
                    if constexpr (BF16) {
                        stc2u(&c16C[b3 * 512 + dq * 128 + tid], tob16(cv));
                    }
                }
                if (dq == 0 && tid < 512) {
                    const float wn = pl_[tid] * rd;
                    stc4(&wBf[b3 * 512 + tid], wn);
                    stc4(&wcB[b3 * 512 + tid], ldc4(&wcB[b3 * 512 + tid]) + wn);
                    outAl[(size_t)b3 * (200 * 512) + (size_t)t * 512 + tid] = wn;
                }
            }
        } else if (bid < 94) {
            if (t >= 1) {
                const int jo = (bid - 64) * 8 + (wid >> 1);
                const int bh = wid & 1;
                const float* pwr = pjw + (size_t)jo * 1536 + lane * 4;
                float a[8] = {0, 0, 0, 0, 0, 0, 0, 0};
                #pragma unroll
                for (int pass = 0; pass < 6; ++pass) {
                    const int k = pass * 256 + lane * 4;
                    const float* qp[8];
                    #pragma unroll
                    for (int i = 0; i < 8; ++i) {
                        const int b = bh * 8 + i;
                        qp[i] = (pass < 4) ? (hdW + b * 1024 + k) : (ctxP + b * 512 + (k - 1024));
                    }
                    float4 c0, c1, c2, c3, c4, c5, c6, c7;
                    LOAD8P_WAIT0(c0, c1, c2, c3, c4, c5, c6, c7,
                                 qp[0], qp[1], qp[2], qp[3], qp[4], qp[5], qp[6], qp[7]);
                    const float4 w4 = *(const float4*)(pwr + pass * 256);
                    a[0] += dot4(w4, c0); a[1] += dot4(w4, c1);
                    a[2] += dot4(w4, c2); a[3] += dot4(w4, c3);
                    a[4] += dot4(w4, c4); a[5] += dot4(w4, c5);
                    a[6] += dot4(w4, c6); a[7] += dot4(w4, c7);
                }
                #pragma unroll
                for (int i = 0; i < 8; ++i)
                    #pragma unroll
                    for (int m = 1; m <= 32; m <<= 1) a[i] += __shfl_xor(a[i], m, 64);
                if (lane == 0) {
                    const int m_ = jo % 80;
                    const int u = (t - 1) * 3 + jo / 80;
                    const float bv = pjb[jo];
                    #pragma unroll
                    for (int i = 0; i < 8; ++i)
                        outMel[(size_t)(bh * 8 + i) * 48000 + m_ * 600 + u] = a[i] + bv;
                }
            }
        }
        grid_barrier(bar, gen); ++gen;
    }
}

extern "C" void kernel_launch(void* const* d_in, const int* in_sizes, int n_in,
                              void* d_out, int out_size, void* d_ws, size_t ws_size,
                              hipStream_t stream)
{
    (void)in_sizes; (void)n_in; (void)out_size;
    const float* mem  = (const float*)d_in[0];
    const float* di   = (const float*)d_in[1];
    const int*   mlen = (const int*)d_in[2];
    const float* pw1  = (const float*)d_in[3];
    const float* pw2  = (const float*)d_in[4];
    const float* awih = (const float*)d_in[5];
    const float* awhh = (const float*)d_in[6];
    const float* abih = (const float*)d_in[7];
    const float* abhh = (const float*)d_in[8];
    const float* dwih = (const float*)d_in[9];
    const float* dwhh = (const float*)d_in[10];
    const float* dbih = (const float*)d_in[11];
    const float* dbhh = (const float*)d_in[12];
    const float* wqp  = (const float*)d_in[13];
    const float* wmp  = (const float*)d_in[14];
    const float* vat  = (const float*)d_in[15];
    const float* cwp  = (const float*)d_in[16];
    const float* ldwp = (const float*)d_in[17];
    const float* pjw  = (const float*)d_in[18];
    const float* pjb  = (const float*)d_in[19];
    float* ws  = (float*)d_ws;
    float* out = (float*)d_out;

    const size_t needB = (size_t)W16_OFF * 4 + (size_t)U16_END * 2;
    const bool useBf16 = (ws_size >= needB);

    hipMemsetAsync(ws + HA_OFF, 0, ZLEN_F * sizeof(float), stream);
    hipLaunchKernelGGL(k_pm, dim3(512), dim3(256), 0, stream, mem, wmp, ws + PM_OFF);
    hipLaunchKernelGGL(k_prenet, dim3(200), dim3(256), 0, stream, di, pw1, pw2, ws + INP_OFF);
    if (useBf16) {
        u16* w16 = (u16*)(ws + W16_OFF);
        // zero shadow state (ha16, hd16, ctx16)
        hipMemsetAsync(w16 + U16_HA, 0, (size_t)(U16_INP - U16_HA) * 2, stream);
        hipLaunchKernelGGL(k_cvt, dim3(512), dim3(256), 0, stream, awih, w16 + U16_AIH, 4096 * 768);
        hipLaunchKernelGGL(k_cvt, dim3(512), dim3(256), 0, stream, awhh, w16 + U16_AHH, 4096 * 1024);
        hipLaunchKernelGGL(k_cvt, dim3(512), dim3(256), 0, stream, dwih, w16 + U16_DIH, 4096 * 1536);
        hipLaunchKernelGGL(k_cvt, dim3(512), dim3(256), 0, stream, dwhh, w16 + U16_DHH, 4096 * 1024);
        // convert prenet output (after k_prenet on same stream)
        hipLaunchKernelGGL(k_cvt, dim3(512), dim3(256), 0, stream, ws + INP_OFF, w16 + U16_INP, 200 * 16 * 256);
    }

    void* args[] = { (void*)&mem, (void*)&mlen, (void*)&awih, (void*)&awhh,
                     (void*)&abih, (void*)&abhh, (void*)&dwih, (void*)&dwhh,
                     (void*)&dbih, (void*)&dbhh, (void*)&wqp, (void*)&vat,
                     (void*)&cwp, (void*)&ldwp, (void*)&pjw, (void*)&pjb,
                     (void*)&ws, (void*)&out };
    if (useBf16)
        hipLaunchCooperativeKernel((const void*)k_main<1>, dim3(256), dim3(1024), args, 0, stream);
    else
        hipLaunchCooperativeKernel((const void*)k_main<0>, dim3(256), dim3(1024), args, 0, stream);
}